// Round 12
// baseline (1102.136 us; speedup 1.0000x reference)
//
#include <hip/hip_runtime.h>

// ---------------------------------------------------------------------------
// AutoregressiveMatrixChain on MI355X, fp32.
// R12 = R11 with a shorter per-iter chain (8 dispatches):
//  - flash does block-level LDS reduce -> 64 psums (4MB); k_cst deleted,
//    fw inline-combines + normalizes from accsm/lsm (L2-hot).
//  - k_combw deleted: slot inlines q from fwP; cb = 128 blocks x 64 codes
//    with inline opv combine; k7 inlines gpre/gc; k9b inlines stopA.
// ---------------------------------------------------------------------------

#define DINL __device__ __forceinline__

DINL float dot4(float4 a, float4 b) {
  return fmaf(a.x, b.x, fmaf(a.y, b.y, fmaf(a.z, b.z, a.w * b.w)));
}
DINL unsigned sortable(float f) {
  unsigned u = __float_as_uint(f);
  return (u & 0x80000000u) ? ~u : (u | 0x80000000u);
}
#define AXPY4(A, W, P) \
  { A.x = fmaf(W, P.x, A.x); A.y = fmaf(W, P.y, A.y); A.z = fmaf(W, P.z, A.z); A.w = fmaf(W, P.w, A.w); }
#define ADD4(A, V) { A.x += V.x; A.y += V.y; A.z += V.z; A.w += V.w; }

// ---------------------------------------------------------------------------
// workspace layout (floats)
// ---------------------------------------------------------------------------
static constexpr int F_CBSQ  = 0;                    // 8192
static constexpr int F_STATE = 8192;                 // 16384
static constexpr int F_WQK   = 24576;                // 1048576
static constexpr int F_T1    = F_WQK + 1048576;      // 1048576
static constexpr int F_WFUSE = F_T1 + 1048576;       // 2105344
static constexpr int F_SQKCP = F_WFUSE + 2105344;    // 36928
static constexpr int F_E     = F_SQKCP + 36928;      // 294912
static constexpr int F_UN    = F_E + 294912;         // union region (8421376)
// setup phase A
static constexpr int F_PMP   = F_UN;                 // 1048576
static constexpr int F_LMP   = F_PMP + 1048576;      // 262144
static constexpr int F_MEAN  = F_LMP + 262144;       // 32768
static constexpr int F_S2P   = F_MEAN + 32768;       // 131072
// setup phase B/C (psums)
static constexpr int F_WQKP  = F_UN;                 // 4194304
static constexpr int F_T1P   = F_UN + 4194304;       // 4194304
static constexpr int F_WFP   = F_UN;                 // 8421376
// per-iter
static constexpr int F_QS1   = F_UN;                 // 131072
static constexpr int F_ACCSM = F_QS1 + 131072;       // 64*16*1024 = 1048576
static constexpr int F_LSM   = F_ACCSM + 1048576;    // 1024
static constexpr int F_FWP   = F_LSM + 1024;         // 16*16*2056 = 526336
static constexpr int F_OPMAX = F_FWP + 526336;       // u64[128*16] = 4096 floats
static constexpr int F_OPIDX = F_OPMAX + 4096;       // 64
static constexpr int F_LPS   = F_OPIDX + 64;         // 4672
static constexpr int F_SSUM  = F_LPS + 4672;         // 16384
static constexpr int F_MS    = F_SSUM + 16384;       // 16384
static constexpr int F_GP    = F_MS + 16384;         // 786432
static constexpr int F_K8P   = F_GP + 786432;        // 262144
static constexpr int F_BIG   = F_K8P + 262144;       // accp 4718592

// ---------------------------------------------------------------------------
// small GEMM (setup only)
// ---------------------------------------------------------------------------
struct SG {
  const float* Bm;
  const float* Bg;
  const float* a0;
  float* out;
  int M, N, Ncore, NB, kslice, ksh, lda, ldb, ldo, mr;
  float scale;
};

template <int MR>
DINL void sgemm_body(const SG p, int bx, float* As) {
  const int t = threadIdx.x;
  const int ks = bx / p.NB, nb = bx % p.NB;
  const int kslice = p.kslice;
  const int kb = ks * kslice;
  const int tot = p.M * kslice;
  for (int idx = t; idx < tot; idx += 256) {
    const int m = idx >> p.ksh;
    const int kl = idx & (kslice - 1);
    As[(m << p.ksh) + kl] = p.a0[m * p.lda + kb + kl];
  }
  __syncthreads();
  const int nl = t & 63, mg = t >> 6;
  const int n = nb * 64 + nl;
  const bool nok = (n < p.N);
  float acc[MR];
#pragma unroll
  for (int i = 0; i < MR; i++) acc[i] = 0.f;
  const bool useg = nok && (n >= p.Ncore);
  const float* Bc = p.Bm + n;
  for (int k4 = 0; k4 < kslice; k4 += 4) {
    float bv[4];
#pragma unroll
    for (int u = 0; u < 4; u++) {
      bv[u] = 0.f;
      if (nok) bv[u] = useg ? p.Bg[kb + k4 + u] : Bc[(kb + k4 + u) * p.ldb];
    }
#pragma unroll
    for (int i = 0; i < MR; i++) {
      const int m = mg + 4 * i;
      if (MR == 4 || m < p.M) {
        const float4 av = *(const float4*)&As[(m << p.ksh) + k4];
        acc[i] = fmaf(av.x, bv[0], acc[i]);
        acc[i] = fmaf(av.y, bv[1], acc[i]);
        acc[i] = fmaf(av.z, bv[2], acc[i]);
        acc[i] = fmaf(av.w, bv[3], acc[i]);
      }
    }
  }
  if (nok) {
#pragma unroll
    for (int i = 0; i < MR; i++) {
      const int m = mg + 4 * i;
      if (MR == 4 || m < p.M) p.out[(ks * p.M + m) * p.ldo + n] = acc[i] * p.scale;
    }
  }
}

__global__ __launch_bounds__(256) void k_sgemm(SG p) {
  __shared__ __align__(16) float As[4352];
  if (p.mr == 4) sgemm_body<4>(p, blockIdx.x, As);
  else sgemm_body<7>(p, blockIdx.x, As);
}

// ---------------------------------------------------------------------------
// 128x128-tile fp32 GEMM core (setup)
// ---------------------------------------------------------------------------
DINL int sw4(int c) { return c ^ (((c >> 5) & 3) << 2); }

__global__ __launch_bounds__(256) void k_wgT(const float* __restrict__ A1,
                                             const float* __restrict__ B,
                                             float* __restrict__ C1P,
                                             const float* __restrict__ A2,
                                             float* __restrict__ C2P) {
  __shared__ __align__(16) float As[16 * 132], Bs[16 * 132];
  const int bx = blockIdx.x;
  const int which = bx >> 8;
  const int rem = bx & 255;
  const int ks = rem >> 6;
  const int tile = rem & 63;
  const int bi = tile >> 3, bj = tile & 7;
  const float* A = which ? A2 : A1;
  float* CP = (which ? C2P : C1P) + ks * 1048576;
  const int t = threadIdx.x;
  const int sr = t >> 2, q4 = t & 3;
  const int tr = (t >> 4) << 3, tc = (t & 15) << 3;
  const int stc0 = sw4(tc), stc1 = sw4(tc + 4);
  float acc[8][8];
#pragma unroll
  for (int i = 0; i < 8; i++)
#pragma unroll
    for (int j = 0; j < 8; j++) acc[i][j] = 0.f;

  const int k00 = ks * 256;
  for (int k0 = k00; k0 < k00 + 256; k0 += 16) {
    __syncthreads();
#pragma unroll
    for (int h = 0; h < 2; h++) {
      const int r = sr + h * 64;
      const float4 av = *(const float4*)&A[(bi * 128 + r) * 1024 + k0 + q4 * 4];
      const float4 bv = *(const float4*)&B[(bj * 128 + r) * 1024 + k0 + q4 * 4];
      As[(q4 * 4 + 0) * 132 + r] = av.x; As[(q4 * 4 + 1) * 132 + r] = av.y;
      As[(q4 * 4 + 2) * 132 + r] = av.z; As[(q4 * 4 + 3) * 132 + r] = av.w;
      const int swr = sw4(r);
      Bs[(q4 * 4 + 0) * 132 + swr] = bv.x; Bs[(q4 * 4 + 1) * 132 + swr] = bv.y;
      Bs[(q4 * 4 + 2) * 132 + swr] = bv.z; Bs[(q4 * 4 + 3) * 132 + swr] = bv.w;
    }
    __syncthreads();
#pragma unroll
    for (int kk = 0; kk < 16; kk++) {
      const float* ar = &As[kk * 132];
      const float* br = &Bs[kk * 132];
      const float4 a0 = *(const float4*)&ar[tr];
      const float4 a1 = *(const float4*)&ar[tr + 4];
      const float4 b0 = *(const float4*)&br[stc0];
      const float4 b1 = *(const float4*)&br[stc1];
      const float a[8] = {a0.x, a0.y, a0.z, a0.w, a1.x, a1.y, a1.z, a1.w};
      const float b[8] = {b0.x, b0.y, b0.z, b0.w, b1.x, b1.y, b1.z, b1.w};
#pragma unroll
      for (int i = 0; i < 8; i++)
#pragma unroll
        for (int j = 0; j < 8; j++) acc[i][j] = fmaf(a[i], b[j], acc[i][j]);
    }
  }
#pragma unroll
  for (int i = 0; i < 8; i++) {
    const int row = bi * 128 + tr + i;
    *(float4*)&CP[row * 1024 + bj * 128 + tc] =
        make_float4(acc[i][0], acc[i][1], acc[i][2], acc[i][3]);
    *(float4*)&CP[row * 1024 + bj * 128 + tc + 4] =
        make_float4(acc[i][4], acc[i][5], acc[i][6], acc[i][7]);
  }
}

__global__ __launch_bounds__(256) void k_combT(const float* __restrict__ C1P,
                                               const float* __restrict__ C2P,
                                               float* __restrict__ C1,
                                               float* __restrict__ C2, float scale) {
  const int bx = blockIdx.x;
  const int half = bx >> 12;
  const int i = ((bx & 4095) << 8) + threadIdx.x;
  const float* src = half ? C2P : C1P;
  float s = 0.f;
#pragma unroll
  for (int ks = 0; ks < 4; ks++) s += src[ks * 1048576 + i];
  (half ? C2 : C1)[i] = s * scale;
}

__global__ __launch_bounds__(256) void k_wgF(const float* __restrict__ Wpv,
                                             const float* __restrict__ Wop,
                                             const float* __restrict__ T1,
                                             float* __restrict__ CfP) {
  __shared__ __align__(16) float As[16 * 132], Bs[16 * 132];
  const int bx = blockIdx.x;
  const int ks = bx >> 7;
  const int rem = bx & 127;
  const int bi = rem >> 4, bj = rem & 15;
  const float* Bsrc = (bj < 8) ? (Wop + bj * 128) : (T1 + (bj - 8) * 128);
  float* CP = CfP + ks * 2105344;
  const int t = threadIdx.x;
  const int sr = t >> 2, q4 = t & 3;
  const int kkq = t >> 4, c8 = (t & 15) << 3;
  const int tr = (t >> 4) << 3, tc = (t & 15) << 3;
  const int stc0 = sw4(tc), stc1 = sw4(tc + 4);
  float acc[8][8];
#pragma unroll
  for (int i = 0; i < 8; i++)
#pragma unroll
    for (int j = 0; j < 8; j++) acc[i][j] = 0.f;

  const int k00 = ks * 256;
  for (int k0 = k00; k0 < k00 + 256; k0 += 16) {
    __syncthreads();
#pragma unroll
    for (int h = 0; h < 2; h++) {
      const int r = sr + h * 64;
      const float4 av = *(const float4*)&Wpv[(bi * 128 + r) * 1024 + k0 + q4 * 4];
      As[(q4 * 4 + 0) * 132 + r] = av.x; As[(q4 * 4 + 1) * 132 + r] = av.y;
      As[(q4 * 4 + 2) * 132 + r] = av.z; As[(q4 * 4 + 3) * 132 + r] = av.w;
    }
    {
      const float4 v0 = *(const float4*)&Bsrc[(k0 + kkq) * 1024 + c8];
      const float4 v1 = *(const float4*)&Bsrc[(k0 + kkq) * 1024 + c8 + 4];
      *(float4*)&Bs[kkq * 132 + sw4(c8)] = v0;
      *(float4*)&Bs[kkq * 132 + sw4(c8 + 4)] = v1;
    }
    __syncthreads();
#pragma unroll
    for (int kk = 0; kk < 16; kk++) {
      const float* ar = &As[kk * 132];
      const float* br = &Bs[kk * 132];
      const float4 a0 = *(const float4*)&ar[tr];
      const float4 a1 = *(const float4*)&ar[tr + 4];
      const float4 b0 = *(const float4*)&br[stc0];
      const float4 b1 = *(const float4*)&br[stc1];
      const float a[8] = {a0.x, a0.y, a0.z, a0.w, a1.x, a1.y, a1.z, a1.w};
      const float b[8] = {b0.x, b0.y, b0.z, b0.w, b1.x, b1.y, b1.z, b1.w};
#pragma unroll
      for (int i = 0; i < 8; i++)
#pragma unroll
        for (int j = 0; j < 8; j++) acc[i][j] = fmaf(a[i], b[j], acc[i][j]);
    }
  }
#pragma unroll
  for (int i = 0; i < 8; i++) {
    const int row = bi * 128 + tr + i;
    *(float4*)&CP[row * 2056 + bj * 128 + tc] =
        make_float4(acc[i][0], acc[i][1], acc[i][2], acc[i][3]);
    *(float4*)&CP[row * 2056 + bj * 128 + tc + 4] =
        make_float4(acc[i][4], acc[i][5], acc[i][6], acc[i][7]);
  }
}

__global__ __launch_bounds__(256) void k_combF(const float* __restrict__ CfP,
                                               float* __restrict__ Cf) {
  const int i2 = blockIdx.x * 256 + threadIdx.x;
  const int r = i2 >> 11, c = i2 & 2047;
  float s = 0.f;
#pragma unroll
  for (int ks = 0; ks < 4; ks++) s += CfP[ks * 2105344 + r * 2056 + c];
  Cf[r * 2056 + c] = s;
}

// gate/stop columns of Wfuse (parallel, 64 blocks, 16-lane row groups)
__global__ __launch_bounds__(256) void k_gs(const float* __restrict__ Wpv,
                                            const float* __restrict__ Wgate,
                                            const float* __restrict__ Wstop,
                                            float* __restrict__ Cf) {
  const int t = threadIdx.x;
  const int row = blockIdx.x * 16 + (t >> 4);
  const int lane = t & 15;
  const float* base = Wpv + row * 1024 + lane * 64;
  const float* gb = Wgate + lane * 64;
  const float* sb = Wstop + lane * 64;
  float g = 0.f, s = 0.f;
#pragma unroll 4
  for (int k = 0; k < 64; k += 4) {
    const float4 av = *(const float4*)&base[k];
    const float4 gv = *(const float4*)&gb[k];
    const float4 sv = *(const float4*)&sb[k];
    g += dot4(av, gv);
    s += dot4(av, sv);
  }
#pragma unroll
  for (int off = 8; off > 0; off >>= 1) {
    g += __shfl_xor(g, off);
    s += __shfl_xor(s, off);
  }
  if (lane == 0) {
    Cf[row * 2056 + 2048] = g;
    Cf[row * 2056 + 2049] = s;
  }
}

// ---------------------------------------------------------------------------
// setup: E[b][k][9] = exp(sqk_j . p_bk). grid (32,16), 512 threads.
// ---------------------------------------------------------------------------
__global__ __launch_bounds__(512) void k_E(const float* __restrict__ prompt,
                                           const float* __restrict__ sqkcP,
                                           float* __restrict__ E) {
  __shared__ __align__(16) char qsm[36864];
  const int b = blockIdx.y, kc = blockIdx.x;
  const int t = threadIdx.x;
  for (int idx = t; idx < 9216; idx += 512) {
    const int j = idx >> 10, h = idx & 1023;
    float s = 0.f;
    for (int sp = 0; sp < 4; sp++) s += sqkcP[(sp * 9 + j) * 1025 + h];
    const int x = idx << 2;
    *(float*)(qsm + (x ^ (((x >> 7) & 7) << 4))) = s;
  }
  __syncthreads();
  const int w = t >> 6, l = t & 63;
  const int bxl = 64 * l;
  const int key = ((bxl >> 7) & 7) << 4;
  const int o0 = bxl ^ key, o1 = (bxl + 16) ^ key, o2 = (bxl + 32) ^ key, o3 = (bxl + 48) ^ key;
  const int k0 = kc * 64 + w * 8;
  const float* pbase = prompt + ((b * 2048 + k0) << 10) + 16 * l;
  for (int ki = 0; ki < 8; ki++) {
    const float4* pr = (const float4*)(pbase + (ki << 10));
    const float4 p0 = pr[0], p1 = pr[1], p2 = pr[2], p3 = pr[3];
    float sj[9];
#pragma unroll
    for (int j = 0; j < 9; j++) {
      const char* qp = qsm + (j << 12);
      sj[j] = dot4(*(const float4*)(qp + o0), p0) + dot4(*(const float4*)(qp + o1), p1) +
              dot4(*(const float4*)(qp + o2), p2) + dot4(*(const float4*)(qp + o3), p3);
    }
#pragma unroll
    for (int off = 32; off > 0; off >>= 1) {
#pragma unroll
      for (int j = 0; j < 9; j++) sj[j] += __shfl_xor(sj[j], off);
    }
    float wv = sj[0];
#pragma unroll
    for (int j = 1; j < 9; j++)
      if (l == j) wv = sj[j];
    if (l < 9) E[(b * 2048 + k0 + ki) * 9 + l] = __expf(wv);
  }
}

// --------------------------- setup small kernels ---------------------------
__global__ __launch_bounds__(256) void k_meanpsum(const float* __restrict__ src,
                                                  float* __restrict__ out, int rpc) {
  const int s = blockIdx.x, b = blockIdx.y, t = threadIdx.x;
  const int R = gridDim.x * rpc;
  const float4* base = (const float4*)src + (size_t)(b * R + s * rpc) * 256 + t;
  float4 acc = make_float4(0.f, 0.f, 0.f, 0.f);
#pragma unroll 4
  for (int r = 0; r < rpc; r++) {
    const float4 v = base[r * 256];
    ADD4(acc, v);
  }
  ((float4*)out)[((s * 16 + b) << 8) + t] = acc;
}

__global__ __launch_bounds__(256) void k_cbsq(const float* __restrict__ cbv,
                                              float* __restrict__ out) {
  const int c = blockIdx.x * 4 + (threadIdx.x >> 6);
  const int l = threadIdx.x & 63;
  const float4* cr = (const float4*)(cbv + (c << 10));
  float s = 0.f;
#pragma unroll
  for (int r = 0; r < 4; r++) {
    const float4 v = cr[4 * l + r];
    s += dot4(v, v);
  }
#pragma unroll
  for (int off = 32; off > 0; off >>= 1) s += __shfl_xor(s, off);
  if (l == 0) out[c] = s;
}

__global__ __launch_bounds__(256) void k_meancat(const float* __restrict__ pmp,
                                                 const float* __restrict__ lmp,
                                                 float* __restrict__ mean) {
  const int gi = blockIdx.x * 256 + threadIdx.x;
  const int b = gi >> 11, k = gi & 2047;
  float v = 0.f;
  if (k < 1024) {
    for (int s = 0; s < 64; s++) v += pmp[((s * 16 + b) << 10) + k];
    v *= (1.f / 2048.f);
  } else {
    const int kk = k - 1024;
    for (int s = 0; s < 16; s++) v += lmp[((s * 16 + b) << 10) + kk];
    v *= (1.f / 512.f);
  }
  mean[b * 2048 + k] = v;
}

__global__ __launch_bounds__(256) void k_s2b(const float* __restrict__ s2p,
                                             float* __restrict__ state) {
  const int gi = blockIdx.x * 256 + threadIdx.x;
  const int b = gi >> 10, h = gi & 1023;
  float s = 0.f;
  for (int si = 0; si < 8; si++) s += s2p[((si * 16 + b) << 10) + h];
  state[gi] = tanhf(s);
}

// ===========================================================================
// per-iteration phase bodies
// ===========================================================================

DINL void ph_qs1(int bx, char* smemc, const float* state, const float* Wqk,
                 float* outP) {
  float* As = (float*)smemc;
  const int t = threadIdx.x;
  const int ks = bx >> 4, nb = bx & 15;
  const int kb = ks * 128;
  for (int idx = t; idx < 2048; idx += 256)
    As[idx] = state[((idx >> 7) << 10) + kb + (idx & 127)];
  __syncthreads();
  const int nl = t & 63, mg = t >> 6;
  const int n = nb * 64 + nl;
  const float* Bc = Wqk + n;
  float acc[4] = {0.f, 0.f, 0.f, 0.f};
  for (int k4 = 0; k4 < 128; k4 += 4) {
    float bv[4];
#pragma unroll
    for (int u = 0; u < 4; u++) bv[u] = Bc[(kb + k4 + u) << 10];
#pragma unroll
    for (int i = 0; i < 4; i++) {
      const float4 av = *(const float4*)&As[((mg + 4 * i) << 7) + k4];
      acc[i] = fmaf(av.x, bv[0], acc[i]);
      acc[i] = fmaf(av.y, bv[1], acc[i]);
      acc[i] = fmaf(av.z, bv[2], acc[i]);
      acc[i] = fmaf(av.w, bv[3], acc[i]);
    }
  }
#pragma unroll
  for (int i = 0; i < 4; i++)
    outP[((ks * 16 + mg + 4 * i) << 10) + n] = acc[i];
}

// flash state attention with block-level reduce: grid (64,16).
// block g covers keys g*32 + w*8 .. +8 per wave; LDS-reduces 4 waves ->
// accsm[(b*64+g)*1024], lsm[b*64+g].
DINL void ph_flash(int g, int b, char* smemc, const float* prompt,
                   const float* qs1P, float* accsm, float* lsm) {
  float* red = (float*)smemc;            // 4*1024 floats
  float* lred = (float*)(smemc + 16384); // 4 floats
  const int t = threadIdx.x;
  const int w = t >> 6, l = t & 63;
  float4 q0 = make_float4(0.f, 0.f, 0.f, 0.f), q1 = q0, q2 = q0, q3 = q0;
#pragma unroll
  for (int s = 0; s < 8; s++) {
    const float4* qp = (const float4*)(qs1P + ((s * 16 + b) << 10) + 16 * l);
    ADD4(q0, qp[0]); ADD4(q1, qp[1]); ADD4(q2, qp[2]); ADD4(q3, qp[3]);
  }
  float4 acc[4];
#pragma unroll
  for (int r = 0; r < 4; r++) acc[r] = make_float4(0.f, 0.f, 0.f, 0.f);
  float lsum = 0.f;
  const int k0 = g * 32 + w * 8;
  const float* pbase = prompt + ((b * 2048 + k0) << 10) + 16 * l;
#pragma unroll 2
  for (int k = 0; k < 8; k++) {
    const float4* pr = (const float4*)(pbase + (k << 10));
    const float4 p0 = pr[0], p1 = pr[1], p2 = pr[2], p3 = pr[3];
    float s = dot4(q0, p0) + dot4(q1, p1) + dot4(q2, p2) + dot4(q3, p3);
#pragma unroll
    for (int off = 32; off > 0; off >>= 1) s += __shfl_xor(s, off);
    const float wgt = __expf(s);
    lsum += wgt;
    AXPY4(acc[0], wgt, p0); AXPY4(acc[1], wgt, p1);
    AXPY4(acc[2], wgt, p2); AXPY4(acc[3], wgt, p3);
  }
  float4* myr = (float4*)(red + w * 1024 + 16 * l);
  myr[0] = acc[0]; myr[1] = acc[1]; myr[2] = acc[2]; myr[3] = acc[3];
  if (l == 0) lred[w] = lsum;
  __syncthreads();
  // cross-wave reduce: thread t covers h = t*4..t*4+3
  float4 s0 = *(float4*)(red + t * 4);
  const float4 s1 = *(float4*)(red + 1024 + t * 4);
  const float4 s2 = *(float4*)(red + 2048 + t * 4);
  const float4 s3 = *(float4*)(red + 3072 + t * 4);
  ADD4(s0, s1); ADD4(s0, s2); ADD4(s0, s3);
  *(float4*)&accsm[((b * 64 + g) << 10) + t * 4] = s0;
  if (t == 0) lsm[b * 64 + g] = lred[0] + lred[1] + lred[2] + lred[3];
}

// fw: ctx@Wfuse with inline combine of 64 flash psums + 1/l normalize.
DINL void ph_fw(int bx, char* smemc, const float* accsm, const float* lsm,
                const float* wfuse, float* outp) {
  float* As = (float*)smemc;            // 1024 floats
  float* rl = (float*)(smemc + 4096);   // 16 floats
  const int t = threadIdx.x;
  const int ks = bx / 33, nb = bx % 33;
  const int kb = ks * 64;
  if (t < 16) {
    float s = 0.f;
    for (int g = 0; g < 64; g++) s += lsm[t * 64 + g];
    rl[t] = 1.f / s;
  }
  __syncthreads();
  for (int idx = t; idx < 1024; idx += 256) {
    const int m = idx >> 6;
    const int h = kb + (idx & 63);
    float s = 0.f;
    for (int g = 0; g < 64; g++) s += accsm[((m * 64 + g) << 10) + h];
    As[idx] = s * rl[m];
  }
  __syncthreads();
  const int nl = t & 63, mg = t >> 6;
  const int n = nb * 64 + nl;
  const bool nok = (n < 2050);
  const float* Bc = wfuse + n;
  float acc[4] = {0.f, 0.f, 0.f, 0.f};
  for (int k4 = 0; k4 < 64; k4 += 4) {
    float bv[4];
#pragma unroll
    for (int u = 0; u < 4; u++) bv[u] = nok ? Bc[(kb + k4 + u) * 2056] : 0.f;
#pragma unroll
    for (int i = 0; i < 4; i++) {
      const float4 av = *(const float4*)&As[((mg + 4 * i) << 6) + k4];
      acc[i] = fmaf(av.x, bv[0], acc[i]);
      acc[i] = fmaf(av.y, bv[1], acc[i]);
      acc[i] = fmaf(av.z, bv[2], acc[i]);
      acc[i] = fmaf(av.w, bv[3], acc[i]);
    }
  }
  if (nok) {
#pragma unroll
    for (int i = 0; i < 4; i++) outp[(ks * 16 + mg + 4 * i) * 2056 + n] = acc[i];
  }
}

// slot attention (E-decomposed), q inline-combined from fwP psums.
DINL void ph_slot(int vb, char* smemc, const float* prompt, const float* fwP,
                  const float* E, float* accp, float* lpsum) {
  float* wl = (float*)smemc;
  float* lred = (float*)(smemc + 2560);
  const int kc = vb & 31, b = vb >> 5;
  const int t = threadIdx.x;
  const int w = t >> 6, l = t & 63;
  float4 q0 = make_float4(0.f, 0.f, 0.f, 0.f), q1 = q0, q2 = q0, q3 = q0;
#pragma unroll 4
  for (int p = 0; p < 16; p++) {
    const float4* qp = (const float4*)&fwP[(p * 16 + b) * 2056 + 1024 + 16 * l];
    ADD4(q0, qp[0]); ADD4(q1, qp[1]); ADD4(q2, qp[2]); ADD4(q3, qp[3]);
  }
  const int kbase = kc * 64 + w * 16;
  float lacc = 0.f;
  const float* pbase = prompt + ((b * 2048 + kbase) << 10) + 16 * l;
  for (int ki = 0; ki < 16; ki++) {
    const float4* pr = (const float4*)(pbase + (ki << 10));
    const float4 p0 = pr[0], p1 = pr[1], p2 = pr[2], p3 = pr[3];
    float s = dot4(q0, p0) + dot4(q1, p1) + dot4(q2, p2) + dot4(q3, p3);
#pragma unroll
    for (int off = 32; off > 0; off >>= 1) s += __shfl_xor(s, off);
    const float we = __expf(s);
    if (l < 9) {
      const float wv = we * E[(b * 2048 + kbase + ki) * 9 + l];
      wl[(w * 16 + ki) * 10 + l] = wv;
      lacc += wv;
    }
  }
  if (l < 9) lred[w * 9 + l] = lacc;
  __syncthreads();
  if (t < 9)
    lpsum[(b * 32 + kc) * 9 + t] = lred[t] + lred[9 + t] + lred[18 + t] + lred[27 + t];
  const int h4 = (w << 8) + (l << 2);
  float4 acc[9];
#pragma unroll
  for (int j = 0; j < 9; j++) acc[j] = make_float4(0.f, 0.f, 0.f, 0.f);
  const float* pb2 = prompt + ((b * 2048 + kc * 64) << 10) + h4;
#pragma unroll 2
  for (int k = 0; k < 64; k++) {
    const float4 pv = *(const float4*)(pb2 + (k << 10));
    const float* wr = &wl[k * 10];
#pragma unroll
    for (int j = 0; j < 9; j++) AXPY4(acc[j], wr[j], pv);
  }
  float* ob = accp + (((kc * 16 + b) * 9) << 10) + h4;
#pragma unroll
  for (int j = 0; j < 9; j++) *(float4*)(ob + (j << 10)) = acc[j];
}

// codebook argmax: 128 blocks x 64 codes, opv inline-combined from fwP.
DINL void ph_cb(int vb, char* smemc, const float* fwP, const float* cbv,
                const float* cbsqv, unsigned long long* opmaxp) {
  const int t = threadIdx.x;
  const int w = t >> 6, l = t & 63;
  const int bxl = 64 * l;
  const int key = ((bxl >> 7) & 7) << 4;
  const int o0 = bxl ^ key, o1 = (bxl + 16) ^ key, o2 = (bxl + 32) ^ key, o3 = (bxl + 48) ^ key;
  for (int half = 0; half < 2; half++) {
    __syncthreads();
    for (int idx = t; idx < 8192; idx += 256) {
      const int gi = half * 8192 + idx;
      const int b2 = gi >> 10, h = gi & 1023;
      float s = 0.f;
      for (int p = 0; p < 16; p++) s += fwP[(p * 16 + b2) * 2056 + h];
      const int x = idx << 2;
      *(float*)(smemc + (x ^ (((x >> 7) & 7) << 4))) = s;
    }
    __syncthreads();
    unsigned long long bk[8];
#pragma unroll
    for (int m = 0; m < 8; m++) bk[m] = 0ull;
    const int cbase = (vb << 6) + (w << 4);
    for (int ci = 0; ci < 16; ci++) {
      const int c = cbase + ci;
      const float4* cr = (const float4*)(cbv + (c << 10));
      const float4 c0 = cr[4 * l], c1 = cr[4 * l + 1], c2 = cr[4 * l + 2], c3 = cr[4 * l + 3];
      float sm[8];
#pragma unroll
      for (int m = 0; m < 8; m++) {
        const char* qp = smemc + (m << 12);
        const float4 a0 = *(const float4*)(qp + o0);
        const float4 a1 = *(const float4*)(qp + o1);
        const float4 a2 = *(const float4*)(qp + o2);
        const float4 a3 = *(const float4*)(qp + o3);
        sm[m] = dot4(a0, c0) + dot4(a1, c1) + dot4(a2, c2) + dot4(a3, c3);
      }
#pragma unroll
      for (int off = 32; off > 0; off >>= 1) {
#pragma unroll
        for (int m = 0; m < 8; m++) sm[m] += __shfl_xor(sm[m], off);
      }
      const float cq = cbsqv[c];
#pragma unroll
      for (int m = 0; m < 8; m++) {
        const float sc = fmaf(2.f, sm[m], -cq);
        const unsigned long long k2 =
            ((unsigned long long)sortable(sc) << 32) | (unsigned)(8192 - c);
        bk[m] = k2 > bk[m] ? k2 : bk[m];
      }
    }
    unsigned long long* red = (unsigned long long*)(smemc + 32768);
    __syncthreads();
    if (l == 0) {
#pragma unroll
      for (int m = 0; m < 8; m++) red[w * 8 + m] = bk[m];
    }
    __syncthreads();
    if (t < 8) {
      unsigned long long b2 = red[t];
      for (int ww = 1; ww < 4; ww++) {
        const unsigned long long v = red[ww * 8 + t];
        b2 = v > b2 ? v : b2;
      }
      opmaxp[vb * 16 + half * 8 + t] = b2;
    }
  }
}

// k7: mask + masked mean (0..63), inline gpre/gc; block 64: argmax finish.
DINL void ph_k7(int bx, char* smemc, const float* accp, const float* lpsum,
                const float* fwP, const float* sqkcP, const float* bgate,
                const unsigned long long* opmax, int* opidx, float* ssum) {
  unsigned long long* red = (unsigned long long*)smemc;
  float* rl = (float*)(smemc + 2048);
  float* gpre = (float*)(smemc + 2112);
  float* gcs = (float*)(smemc + 2192);
  int* mask_s = (int*)(smemc + 2240);
  float* cntInvp = (float*)(smemc + 2288);
  const int t = threadIdx.x;
  if (bx == 64) {
    const int b = t & 15, part = t >> 4;
    unsigned long long best = 0ull;
    for (int c = part * 8; c < part * 8 + 8; c++) {
      const unsigned long long v = opmax[c * 16 + b];
      best = v > best ? v : best;
    }
    red[t] = best;
    __syncthreads();
    if (t < 16) {
      unsigned long long m = red[t];
      for (int p2 = 1; p2 < 16; p2++) {
        const unsigned long long v = red[p2 * 16 + t];
        m = v > m ? v : m;
      }
      opidx[t] = 8192 - (int)(unsigned)(m & 0xFFFFFFFFull);
    }
    return;
  }
  const int b = bx >> 2;
  if (t < 9) {
    float s = 0.f;
    for (int c = 0; c < 32; c++) s += lpsum[(b * 32 + c) * 9 + t];
    rl[t] = 1.f / s;
  }
  if (t >= 32 && t < 48) {
    float g = 0.f;
    for (int p = 0; p < 16; p++) g += fwP[(p * 16 + (t - 32)) * 2056 + 2048];
    gpre[t - 32] = g;
  }
  if (t >= 48 && t < 57) {
    float g = 0.f;
    for (int sp = 0; sp < 4; sp++) g += sqkcP[(sp * 9 + (t - 48)) * 1025 + 1024];
    gcs[t - 48] = g;
  }
  __syncthreads();
  if (t == 0) {
    const float bg = bgate[0];
    bool any = false;
    for (int bb = 0; bb < 16; bb++)
      for (int j = 0; j < 9; j++)
        if (gpre[bb] + gcs[j] + bg >= 0.f) any = true;
    int cnt = 0;
    if (any) {
      for (int j = 0; j < 9; j++) {
        const int s = (gpre[b] + gcs[j] + bg >= 0.f) ? 1 : 0;
        mask_s[j] = s;
        cnt += s;
      }
    } else {
      float bv = -3.4e38f;
      int bj = 0;
      for (int j = 0; j < 9; j++) {
        const float v = gpre[b] + gcs[j] + bg;
        if (v > bv) { bv = v; bj = j; }
      }
      for (int j = 0; j < 9; j++) mask_s[j] = (j == bj) ? 1 : 0;
      cnt = 1;
    }
    cntInvp[0] = 1.f / (float)(cnt > 0 ? cnt : 1);
  }
  __syncthreads();
  const int h = ((bx & 3) << 8) + t;
  float v = 0.f;
  for (int j = 0; j < 9; j++) {
    if (mask_s[j]) {
      float s = 0.f;
      for (int c = 0; c < 32; c++) s += accp[(((c * 16 + b) * 9 + j) << 10) + h];
      v = fmaf(s, rl[j], v);
    }
  }
  ssum[(b << 10) + h] = v * cntInvp[0];
}

DINL void ph_k8p(int bx, char* smemc, const float* ssum, const float* Wpv,
                 float* outP) {
  float* As = (float*)smemc;
  const int t = threadIdx.x;
  const int ks = bx >> 4, nb = bx & 15;
  const int kb = ks * 64;
  for (int idx = t; idx < 1024; idx += 256)
    As[idx] = ssum[((idx >> 6) << 10) + kb + (idx & 63)];
  __syncthreads();
  const int nl = t & 63, mg = t >> 6;
  const int n = nb * 64 + nl;
  const float* Bc = Wpv + n;
  float acc[4] = {0.f, 0.f, 0.f, 0.f};
  for (int k4 = 0; k4 < 64; k4 += 4) {
    float bv[4];
#pragma unroll
    for (int u = 0; u < 4; u++) bv[u] = Bc[(kb + k4 + u) << 10];
#pragma unroll
    for (int i = 0; i < 4; i++) {
      const float4 av = *(const float4*)&As[((mg + 4 * i) << 6) + k4];
      acc[i] = fmaf(av.x, bv[0], acc[i]);
      acc[i] = fmaf(av.y, bv[1], acc[i]);
      acc[i] = fmaf(av.z, bv[2], acc[i]);
      acc[i] = fmaf(av.w, bv[3], acc[i]);
    }
  }
#pragma unroll
  for (int i = 0; i < 4; i++)
    outP[((ks * 16 + mg + 4 * i) << 10) + n] = acc[i];
}

DINL void ph_gru(int bx, char* smemc, const float* k8p, const int* opidx,
                 const float* cbv, const float* state, const float* Wih,
                 const float* Whh, float* gpP, float* ms, float* dout, int it) {
  float* As = (float*)smemc;
  const int t = threadIdx.x;
  const int half = (bx >= 384) ? 1 : 0;
  const int b2 = half ? bx - 384 : bx;
  const int ks = b2 / 48, nb = b2 % 48;
  const int kb = ks * 128;
  for (int idx = t; idx < 2048; idx += 256) {
    const int m = idx >> 7, kl = idx & 127;
    float v;
    if (!half) {
      float s = 0.f;
      for (int p = 0; p < 16; p++) s += k8p[((p * 16 + m) << 10) + kb + kl];
      v = tanhf(s + cbv[(opidx[m] << 10) + kb + kl]);
      if (nb == 0) {
        ms[(m << 10) + kb + kl] = v;
        dout[(m << 12) + (it << 10) + kb + kl] = v;
      }
    } else {
      v = state[(m << 10) + kb + kl];
    }
    As[idx] = v;
  }
  __syncthreads();
  const int nl = t & 63, mg = t >> 6;
  const int n = nb * 64 + nl;
  const float* Bc = (half ? Whh : Wih) + n;
  float acc[4] = {0.f, 0.f, 0.f, 0.f};
  for (int k4 = 0; k4 < 128; k4 += 4) {
    float bv[4];
#pragma unroll
    for (int u = 0; u < 4; u++) bv[u] = Bc[(kb + k4 + u) * 3072];
#pragma unroll
    for (int i = 0; i < 4; i++) {
      const float4 av = *(const float4*)&As[((mg + 4 * i) << 7) + k4];
      acc[i] = fmaf(av.x, bv[0], acc[i]);
      acc[i] = fmaf(av.y, bv[1], acc[i]);
      acc[i] = fmaf(av.z, bv[2], acc[i]);
      acc[i] = fmaf(av.w, bv[3], acc[i]);
    }
  }
  float* outp = gpP + half * 3072;
#pragma unroll
  for (int i = 0; i < 4; i++) outp[(ks * 16 + mg + 4 * i) * 6144 + n] = acc[i];
}

DINL void ph_k9b(int bx, const float* gp, const float* bih, const float* bhh,
                 float* state, const float* fwP, const float* ms,
                 const float* Wstop, const float* bstop, float* dout, int it) {
  const int t = threadIdx.x;
  if (bx < 64) {
    const int gi = bx * 256 + t;
    const int b = gi >> 10, h = gi & 1023;
    float ir = 0.f, iz = 0.f, inn = 0.f, hr = 0.f, hz = 0.f, hn = 0.f;
    for (int s = 0; s < 8; s++) {
      const float* g = gp + (s * 16 + b) * 6144;
      ir += g[h]; iz += g[1024 + h]; inn += g[2048 + h];
      hr += g[3072 + h]; hz += g[4096 + h]; hn += g[5120 + h];
    }
    ir += bih[h]; iz += bih[1024 + h]; inn += bih[2048 + h];
    hr += bhh[h]; hz += bhh[1024 + h]; hn += bhh[2048 + h];
    const float r = 1.f / (1.f + __expf(-(ir + hr)));
    const float z = 1.f / (1.f + __expf(-(iz + hz)));
    const float n = tanhf(fmaf(r, hn, inn));
    const float hold = state[gi];
    state[gi] = (1.f - z) * n + z * hold;
  } else {
    const int wid = (bx - 64) * 4 + (t >> 6);
    const int l = t & 63;
    float p = 0.f;
    for (int i = 0; i < 16; i++) {
      const int h = l + (i << 6);
      p = fmaf(ms[(wid << 10) + h], Wstop[1024 + h], p);
    }
#pragma unroll
    for (int off = 32; off > 0; off >>= 1) p += __shfl_xor(p, off);
    if (l == 0) {
      float sa = 0.f;
      for (int pp = 0; pp < 16; pp++) sa += fwP[(pp * 16 + wid) * 2056 + 2049];
      const float lg = p + sa + bstop[0];
      dout[65536 + wid * 4 + it] = lg;
      dout[65600 + wid * 4 + it] = 1.f / (1.f + __expf(-lg));
    }
  }
}

// ===========================================================================
// per-iteration kernels
// ===========================================================================
__global__ __launch_bounds__(256) void kf_qs1(const float* state, const float* Wqk, float* outP) {
  __shared__ __align__(16) char smem[8192];
  ph_qs1(blockIdx.x, smem, state, Wqk, outP);
}
__global__ __launch_bounds__(256) void kf_flash(const float* prompt, const float* qs1P,
                                                float* accsm, float* lsm) {
  __shared__ __align__(16) char smem[16416];
  ph_flash(blockIdx.x, blockIdx.y, smem, prompt, qs1P, accsm, lsm);
}
__global__ __launch_bounds__(256) void kf_fw(const float* accsm, const float* lsm,
                                             const float* wfuse, float* outp) {
  __shared__ __align__(16) char smem[4160];
  ph_fw(blockIdx.x, smem, accsm, lsm, wfuse, outp);
}
// merged slot (blocks 0..511) + codebook argmax (512..639)
__global__ __launch_bounds__(256) void k_slotcb(const float* prompt, const float* fwP,
                                                const float* E, float* accp, float* lpsum,
                                                const float* cbv, const float* cbsqv,
                                                unsigned long long* opmaxp) {
  __shared__ __align__(16) char smem[33024];
  const int bx = blockIdx.x;
  if (bx < 512) ph_slot(bx, smem, prompt, fwP, E, accp, lpsum);
  else ph_cb(bx - 512, smem, fwP, cbv, cbsqv, opmaxp);
}
__global__ __launch_bounds__(256) void kf_k7(const float* accp, const float* lpsum,
                                             const float* fwP, const float* sqkcP,
                                             const float* bgate,
                                             const unsigned long long* opmax,
                                             int* opidx, float* ssum) {
  __shared__ __align__(16) char smem[2304];
  ph_k7(blockIdx.x, smem, accp, lpsum, fwP, sqkcP, bgate, opmax, opidx, ssum);
}
__global__ __launch_bounds__(256) void kf_k8p(const float* ssum, const float* Wpv, float* outP) {
  __shared__ __align__(16) char smem[4096];
  ph_k8p(blockIdx.x, smem, ssum, Wpv, outP);
}
__global__ __launch_bounds__(256) void kf_gru(const float* k8p, const int* opidx,
                                              const float* cbv, const float* state,
                                              const float* Wih, const float* Whh,
                                              float* gpP, float* ms, float* dout, int it) {
  __shared__ __align__(16) char smem[8192];
  ph_gru(blockIdx.x, smem, k8p, opidx, cbv, state, Wih, Whh, gpP, ms, dout, it);
}
__global__ __launch_bounds__(256) void kf_k9b(const float* gp, const float* bih,
                                              const float* bhh, float* state,
                                              const float* fwP, const float* ms,
                                              const float* Wstop, const float* bstop,
                                              float* dout, int it) {
  ph_k9b(blockIdx.x, gp, bih, bhh, state, fwP, ms, Wstop, bstop, dout, it);
}
__global__ void kf_k10(float* __restrict__ dout) {
  const int t = threadIdx.x;
  if (t < 16) {
    int cl = 4;
    for (int it = 0; it < 4; it++) {
      if (dout[65536 + t * 4 + it] >= 0.f) { cl = it + 1; break; }
    }
    dout[65664 + t] = (float)cl;
  }
}

// ===========================================================================
// host
// ===========================================================================
static SG baseSG() {
  SG p;
  p.Bm = nullptr; p.Bg = nullptr; p.a0 = nullptr; p.out = nullptr;
  p.M = 16; p.N = 1024; p.Ncore = 1024;
  p.NB = 16; p.kslice = 64; p.ksh = 6;
  p.lda = 1024; p.ldb = 1024; p.ldo = 1024;
  p.mr = 4; p.scale = 1.f;
  return p;
}

extern "C" void kernel_launch(void* const* d_in, const int* in_sizes, int n_in,
                              void* d_out, int out_size, void* d_ws, size_t ws_size,
                              hipStream_t stream) {
  (void)in_sizes; (void)n_in; (void)out_size; (void)ws_size;
  const float* logic  = (const float*)d_in[0];
  const float* prompt = (const float*)d_in[1];
  const float* cbv    = (const float*)d_in[2];
  const float* W_init = (const float*)d_in[3];
  const float* W_pq   = (const float*)d_in[4];
  const float* W_pk   = (const float*)d_in[5];
  const float* W_pv   = (const float*)d_in[6];
  const float* slotq  = (const float*)d_in[7];
  const float* W_sq   = (const float*)d_in[8];
  const float* W_op   = (const float*)d_in[9];
  const float* W_gate = (const float*)d_in[10];
  const float* b_gate = (const float*)d_in[11];
  const float* W_stop = (const float*)d_in[12];
  const float* b_stop = (const float*)d_in[13];
  const float* Wih    = (const float*)d_in[14];
  const float* Whh    = (const float*)d_in[15];
  const float* bih    = (const float*)d_in[16];
  const float* bhh    = (const float*)d_in[17];
  float* out = (float*)d_out;
  float* w = (float*)d_ws;

  const float inv32 = 1.0f / 32.0f;

  // ---- setup phase A ----
  k_meanpsum<<<dim3(64, 16), 256, 0, stream>>>(prompt, w + F_PMP, 32);
  k_meanpsum<<<dim3(16, 16), 256, 0, stream>>>(logic, w + F_LMP, 32);
  k_cbsq<<<2048, 256, 0, stream>>>(cbv, w + F_CBSQ);
  k_gs<<<64, 256, 0, stream>>>(W_pv, W_gate, W_stop, w + F_WFUSE);
  k_meancat<<<128, 256, 0, stream>>>(w + F_PMP, w + F_LMP, w + F_MEAN);
  {
    SG p = baseSG();
    p.a0 = w + F_MEAN; p.Bm = W_init; p.out = w + F_S2P;
    p.kslice = 256; p.ksh = 8; p.lda = 2048; p.NB = 16;
    k_sgemm<<<128, 256, 0, stream>>>(p);
  }
  k_s2b<<<64, 256, 0, stream>>>(w + F_S2P, w + F_STATE);
  // ---- setup phase B: Wqk, T1 ----
  k_wgT<<<512, 256, 0, stream>>>(W_pq, W_pk, w + F_WQKP, W_sq, w + F_T1P);
  k_combT<<<8192, 256, 0, stream>>>(w + F_WQKP, w + F_T1P, w + F_WQK, w + F_T1, inv32);
  {
    SG p = baseSG();
    p.a0 = slotq; p.Bm = w + F_T1; p.Bg = W_gate;
    p.M = 9; p.N = 1025; p.Ncore = 1024; p.NB = 17;
    p.kslice = 256; p.ksh = 8; p.out = w + F_SQKCP; p.ldo = 1025; p.mr = 7;
    k_sgemm<<<68, 256, 0, stream>>>(p);
  }
  k_E<<<dim3(32, 16), 512, 0, stream>>>(prompt, w + F_SQKCP, w + F_E);
  // ---- setup phase C: Wfuse cols 0..2047 ----
  k_wgF<<<512, 256, 0, stream>>>(W_pv, W_op, w + F_T1, w + F_WFP);
  k_combF<<<8192, 256, 0, stream>>>(w + F_WFP, w + F_WFUSE);

  // ---- iteration loop (8 dispatches/iter) ----
  for (int it = 0; it < 4; ++it) {
    kf_qs1<<<128, 256, 0, stream>>>(w + F_STATE, w + F_WQK, w + F_QS1);
    kf_flash<<<dim3(64, 16), 256, 0, stream>>>(prompt, w + F_QS1,
                                               w + F_ACCSM, w + F_LSM);
    kf_fw<<<528, 256, 0, stream>>>(w + F_ACCSM, w + F_LSM, w + F_WFUSE, w + F_FWP);
    k_slotcb<<<640, 256, 0, stream>>>(prompt, w + F_FWP, w + F_E,
                                      w + F_BIG, w + F_LPS, cbv, w + F_CBSQ,
                                      (unsigned long long*)(w + F_OPMAX));
    kf_k7<<<65, 256, 0, stream>>>(w + F_BIG, w + F_LPS, w + F_FWP, w + F_SQKCP,
                                  b_gate, (const unsigned long long*)(w + F_OPMAX),
                                  (int*)(w + F_OPIDX), w + F_SSUM);
    kf_k8p<<<256, 256, 0, stream>>>(w + F_SSUM, W_pv, w + F_K8P);
    kf_gru<<<768, 256, 0, stream>>>(w + F_K8P, (const int*)(w + F_OPIDX), cbv,
                                    w + F_STATE, Wih, Whh, w + F_GP, w + F_MS,
                                    out, it);
    kf_k9b<<<68, 256, 0, stream>>>(w + F_GP, bih, bhh, w + F_STATE, w + F_FWP,
                                   w + F_MS, W_stop, b_stop, out, it);
  }
  kf_k10<<<1, 64, 0, stream>>>(out);
}

// Round 13
// 798.596 us; speedup vs baseline: 1.3801x; 1.3801x over previous
//
#include <hip/hip_runtime.h>

// ---------------------------------------------------------------------------
// AutoregressiveMatrixChain on MI355X, fp32.
// R13: per-iter loop = R11 structure (10 dispatches, combw restored) + flash
// block-level reduce (accsm 4MB) with adapted cst. Setup merged 13 -> 4
// dispatches (block-range concatenation, dedicated buffers, no aliasing).
// ---------------------------------------------------------------------------

#define DINL __device__ __forceinline__

DINL float dot4(float4 a, float4 b) {
  return fmaf(a.x, b.x, fmaf(a.y, b.y, fmaf(a.z, b.z, a.w * b.w)));
}
DINL unsigned sortable(float f) {
  unsigned u = __float_as_uint(f);
  return (u & 0x80000000u) ? ~u : (u | 0x80000000u);
}
#define AXPY4(A, W, P) \
  { A.x = fmaf(W, P.x, A.x); A.y = fmaf(W, P.y, A.y); A.z = fmaf(W, P.z, A.z); A.w = fmaf(W, P.w, A.w); }
#define ADD4(A, V) { A.x += V.x; A.y += V.y; A.z += V.z; A.w += V.w; }

// ---------------------------------------------------------------------------
// workspace layout (floats) - no aliasing, ~30.4M floats = 122 MB
// ---------------------------------------------------------------------------
static constexpr int F_CBSQ  = 0;                    // 8192
static constexpr int F_STATE = F_CBSQ + 8192;        // 16384
static constexpr int F_WQK   = F_STATE + 16384;      // 1048576
static constexpr int F_T1    = F_WQK + 1048576;      // 1048576
static constexpr int F_WFUSE = F_T1 + 1048576;       // 2105344
static constexpr int F_SQKCP = F_WFUSE + 2105344;    // 36928
static constexpr int F_E     = F_SQKCP + 36928;      // 294912
static constexpr int F_PMP   = F_E + 294912;         // 1048576
static constexpr int F_LMP   = F_PMP + 1048576;      // 262144
static constexpr int F_MEAN  = F_LMP + 262144;       // 32768
static constexpr int F_S2P   = F_MEAN + 32768;       // 131072
static constexpr int F_WQKP  = F_S2P + 131072;       // 4194304
static constexpr int F_T1P   = F_WQKP + 4194304;     // 4194304
static constexpr int F_WFP   = F_T1P + 4194304;      // 8421376
static constexpr int F_QS1   = F_WFP + 8421376;      // 131072
static constexpr int F_ACCSM = F_QS1 + 131072;       // 1048576
static constexpr int F_LSM   = F_ACCSM + 1048576;    // 1024
static constexpr int F_CTX   = F_LSM + 1024;         // 16384
static constexpr int F_FWP   = F_CTX + 16384;        // 526336
static constexpr int F_OPV   = F_FWP + 526336;       // 16384
static constexpr int F_OPMAX = F_OPV + 16384;        // u64[8192] = 16384 floats
static constexpr int F_OPIDX = F_OPMAX + 16384;      // 64
static constexpr int F_GPRE  = F_OPIDX + 64;         // 64
static constexpr int F_GC    = F_GPRE + 64;          // 64
static constexpr int F_STOPA = F_GC + 64;            // 64
static constexpr int F_QSLB  = F_STOPA + 64;         // 16384
static constexpr int F_LPS   = F_QSLB + 16384;       // 4672
static constexpr int F_SSUM  = F_LPS + 4672;         // 16384
static constexpr int F_MS    = F_SSUM + 16384;       // 16384
static constexpr int F_GP    = F_MS + 16384;         // 786432
static constexpr int F_K8P   = F_GP + 786432;        // 262144
static constexpr int F_ACCP  = F_K8P + 262144;       // 4718592

// ---------------------------------------------------------------------------
// small GEMM body (setup: init-GEMM + sqkc)
// ---------------------------------------------------------------------------
struct SG {
  const float* Bm;
  const float* Bg;
  const float* a0;
  float* out;
  int M, N, Ncore, NB, kslice, ksh, lda, ldb, ldo, mr;
  float scale;
};

template <int MR>
DINL void sgemm_body(const SG p, int bx, float* As) {
  const int t = threadIdx.x;
  const int ks = bx / p.NB, nb = bx % p.NB;
  const int kslice = p.kslice;
  const int kb = ks * kslice;
  const int tot = p.M * kslice;
  for (int idx = t; idx < tot; idx += 256) {
    const int m = idx >> p.ksh;
    const int kl = idx & (kslice - 1);
    As[(m << p.ksh) + kl] = p.a0[m * p.lda + kb + kl];
  }
  __syncthreads();
  const int nl = t & 63, mg = t >> 6;
  const int n = nb * 64 + nl;
  const bool nok = (n < p.N);
  float acc[MR];
#pragma unroll
  for (int i = 0; i < MR; i++) acc[i] = 0.f;
  const bool useg = nok && (n >= p.Ncore);
  const float* Bc = p.Bm + n;
  for (int k4 = 0; k4 < kslice; k4 += 4) {
    float bv[4];
#pragma unroll
    for (int u = 0; u < 4; u++) {
      bv[u] = 0.f;
      if (nok) bv[u] = useg ? p.Bg[kb + k4 + u] : Bc[(kb + k4 + u) * p.ldb];
    }
#pragma unroll
    for (int i = 0; i < MR; i++) {
      const int m = mg + 4 * i;
      if (MR == 4 || m < p.M) {
        const float4 av = *(const float4*)&As[(m << p.ksh) + k4];
        acc[i] = fmaf(av.x, bv[0], acc[i]);
        acc[i] = fmaf(av.y, bv[1], acc[i]);
        acc[i] = fmaf(av.z, bv[2], acc[i]);
        acc[i] = fmaf(av.w, bv[3], acc[i]);
      }
    }
  }
  if (nok) {
#pragma unroll
    for (int i = 0; i < MR; i++) {
      const int m = mg + 4 * i;
      if (MR == 4 || m < p.M) p.out[(ks * p.M + m) * p.ldo + n] = acc[i] * p.scale;
    }
  }
}

// ---------------------------------------------------------------------------
// 128x128-tile fp32 GEMM bodies (setup). sm = 4224-float scratch.
// ---------------------------------------------------------------------------
DINL int sw4(int c) { return c ^ (((c >> 5) & 3) << 2); }

DINL void ph_wgT(int bx, float* sm, const float* __restrict__ A1,
                 const float* __restrict__ B, float* __restrict__ C1P,
                 const float* __restrict__ A2, float* __restrict__ C2P) {
  float* As = sm;
  float* Bs = sm + 2112;
  const int which = bx >> 8;
  const int rem = bx & 255;
  const int ks = rem >> 6;
  const int tile = rem & 63;
  const int bi = tile >> 3, bj = tile & 7;
  const float* A = which ? A2 : A1;
  float* CP = (which ? C2P : C1P) + ks * 1048576;
  const int t = threadIdx.x;
  const int sr = t >> 2, q4 = t & 3;
  const int tr = (t >> 4) << 3, tc = (t & 15) << 3;
  const int stc0 = sw4(tc), stc1 = sw4(tc + 4);
  float acc[8][8];
#pragma unroll
  for (int i = 0; i < 8; i++)
#pragma unroll
    for (int j = 0; j < 8; j++) acc[i][j] = 0.f;

  const int k00 = ks * 256;
  for (int k0 = k00; k0 < k00 + 256; k0 += 16) {
    __syncthreads();
#pragma unroll
    for (int h = 0; h < 2; h++) {
      const int r = sr + h * 64;
      const float4 av = *(const float4*)&A[(bi * 128 + r) * 1024 + k0 + q4 * 4];
      const float4 bv = *(const float4*)&B[(bj * 128 + r) * 1024 + k0 + q4 * 4];
      As[(q4 * 4 + 0) * 132 + r] = av.x; As[(q4 * 4 + 1) * 132 + r] = av.y;
      As[(q4 * 4 + 2) * 132 + r] = av.z; As[(q4 * 4 + 3) * 132 + r] = av.w;
      const int swr = sw4(r);
      Bs[(q4 * 4 + 0) * 132 + swr] = bv.x; Bs[(q4 * 4 + 1) * 132 + swr] = bv.y;
      Bs[(q4 * 4 + 2) * 132 + swr] = bv.z; Bs[(q4 * 4 + 3) * 132 + swr] = bv.w;
    }
    __syncthreads();
#pragma unroll
    for (int kk = 0; kk < 16; kk++) {
      const float* ar = &As[kk * 132];
      const float* br = &Bs[kk * 132];
      const float4 a0 = *(const float4*)&ar[tr];
      const float4 a1 = *(const float4*)&ar[tr + 4];
      const float4 b0 = *(const float4*)&br[stc0];
      const float4 b1 = *(const float4*)&br[stc1];
      const float a[8] = {a0.x, a0.y, a0.z, a0.w, a1.x, a1.y, a1.z, a1.w};
      const float b[8] = {b0.x, b0.y, b0.z, b0.w, b1.x, b1.y, b1.z, b1.w};
#pragma unroll
      for (int i = 0; i < 8; i++)
#pragma unroll
        for (int j = 0; j < 8; j++) acc[i][j] = fmaf(a[i], b[j], acc[i][j]);
    }
  }
#pragma unroll
  for (int i = 0; i < 8; i++) {
    const int row = bi * 128 + tr + i;
    *(float4*)&CP[row * 1024 + bj * 128 + tc] =
        make_float4(acc[i][0], acc[i][1], acc[i][2], acc[i][3]);
    *(float4*)&CP[row * 1024 + bj * 128 + tc + 4] =
        make_float4(acc[i][4], acc[i][5], acc[i][6], acc[i][7]);
  }
}

DINL void ph_wgF(int bx, float* sm, const float* __restrict__ Wpv,
                 const float* __restrict__ Wop, const float* __restrict__ T1,
                 float* __restrict__ CfP) {
  float* As = sm;
  float* Bs = sm + 2112;
  const int ks = bx >> 7;
  const int rem = bx & 127;
  const int bi = rem >> 4, bj = rem & 15;
  const float* Bsrc = (bj < 8) ? (Wop + bj * 128) : (T1 + (bj - 8) * 128);
  float* CP = CfP + ks * 2105344;
  const int t = threadIdx.x;
  const int sr = t >> 2, q4 = t & 3;
  const int kkq = t >> 4, c8 = (t & 15) << 3;
  const int tr = (t >> 4) << 3, tc = (t & 15) << 3;
  const int stc0 = sw4(tc), stc1 = sw4(tc + 4);
  float acc[8][8];
#pragma unroll
  for (int i = 0; i < 8; i++)
#pragma unroll
    for (int j = 0; j < 8; j++) acc[i][j] = 0.f;

  const int k00 = ks * 256;
  for (int k0 = k00; k0 < k00 + 256; k0 += 16) {
    __syncthreads();
#pragma unroll
    for (int h = 0; h < 2; h++) {
      const int r = sr + h * 64;
      const float4 av = *(const float4*)&Wpv[(bi * 128 + r) * 1024 + k0 + q4 * 4];
      As[(q4 * 4 + 0) * 132 + r] = av.x; As[(q4 * 4 + 1) * 132 + r] = av.y;
      As[(q4 * 4 + 2) * 132 + r] = av.z; As[(q4 * 4 + 3) * 132 + r] = av.w;
    }
    {
      const float4 v0 = *(const float4*)&Bsrc[(k0 + kkq) * 1024 + c8];
      const float4 v1 = *(const float4*)&Bsrc[(k0 + kkq) * 1024 + c8 + 4];
      *(float4*)&Bs[kkq * 132 + sw4(c8)] = v0;
      *(float4*)&Bs[kkq * 132 + sw4(c8 + 4)] = v1;
    }
    __syncthreads();
#pragma unroll
    for (int kk = 0; kk < 16; kk++) {
      const float* ar = &As[kk * 132];
      const float* br = &Bs[kk * 132];
      const float4 a0 = *(const float4*)&ar[tr];
      const float4 a1 = *(const float4*)&ar[tr + 4];
      const float4 b0 = *(const float4*)&br[stc0];
      const float4 b1 = *(const float4*)&br[stc1];
      const float a[8] = {a0.x, a0.y, a0.z, a0.w, a1.x, a1.y, a1.z, a1.w};
      const float b[8] = {b0.x, b0.y, b0.z, b0.w, b1.x, b1.y, b1.z, b1.w};
#pragma unroll
      for (int i = 0; i < 8; i++)
#pragma unroll
        for (int j = 0; j < 8; j++) acc[i][j] = fmaf(a[i], b[j], acc[i][j]);
    }
  }
#pragma unroll
  for (int i = 0; i < 8; i++) {
    const int row = bi * 128 + tr + i;
    *(float4*)&CP[row * 2056 + bj * 128 + tc] =
        make_float4(acc[i][0], acc[i][1], acc[i][2], acc[i][3]);
    *(float4*)&CP[row * 2056 + bj * 128 + tc + 4] =
        make_float4(acc[i][4], acc[i][5], acc[i][6], acc[i][7]);
  }
}

// --------------------------- setup small bodies ----------------------------
DINL void ph_meanpsum(int vb, const float* __restrict__ src,
                      float* __restrict__ out, int R) {
  const int s = vb >> 4, b = vb & 15, t = threadIdx.x;
  const float4* base = (const float4*)src + (size_t)(b * R + s * 32) * 256 + t;
  float4 acc = make_float4(0.f, 0.f, 0.f, 0.f);
#pragma unroll 4
  for (int r = 0; r < 32; r++) {
    const float4 v = base[r * 256];
    ADD4(acc, v);
  }
  ((float4*)out)[((s * 16 + b) << 8) + t] = acc;
}

DINL void ph_cbsq(int vb, const float* __restrict__ cbv, float* __restrict__ out) {
  const int c = vb * 4 + (threadIdx.x >> 6);
  const int l = threadIdx.x & 63;
  const float4* cr = (const float4*)(cbv + (c << 10));
  float s = 0.f;
#pragma unroll
  for (int r = 0; r < 4; r++) {
    const float4 v = cr[4 * l + r];
    s += dot4(v, v);
  }
#pragma unroll
  for (int off = 32; off > 0; off >>= 1) s += __shfl_xor(s, off);
  if (l == 0) out[c] = s;
}

DINL void ph_gs(int vb, const float* __restrict__ Wpv, const float* __restrict__ Wgate,
                const float* __restrict__ Wstop, float* __restrict__ Cf) {
  const int t = threadIdx.x;
  const int row = vb * 16 + (t >> 4);
  const int lane = t & 15;
  const float* base = Wpv + row * 1024 + lane * 64;
  const float* gb = Wgate + lane * 64;
  const float* sb = Wstop + lane * 64;
  float g = 0.f, s = 0.f;
#pragma unroll 4
  for (int k = 0; k < 64; k += 4) {
    const float4 av = *(const float4*)&base[k];
    const float4 gv = *(const float4*)&gb[k];
    const float4 sv = *(const float4*)&sb[k];
    g += dot4(av, gv);
    s += dot4(av, sv);
  }
#pragma unroll
  for (int off = 8; off > 0; off >>= 1) {
    g += __shfl_xor(g, off);
    s += __shfl_xor(s, off);
  }
  if (lane == 0) {
    Cf[row * 2056 + 2048] = g;
    Cf[row * 2056 + 2049] = s;
  }
}

DINL void ph_meancat(int vb, const float* __restrict__ pmp,
                     const float* __restrict__ lmp, float* __restrict__ mean) {
  const int gi = vb * 256 + threadIdx.x;
  const int b = gi >> 11, k = gi & 2047;
  float v = 0.f;
  if (k < 1024) {
    for (int s = 0; s < 64; s++) v += pmp[((s * 16 + b) << 10) + k];
    v *= (1.f / 2048.f);
  } else {
    const int kk = k - 1024;
    for (int s = 0; s < 16; s++) v += lmp[((s * 16 + b) << 10) + kk];
    v *= (1.f / 512.f);
  }
  mean[b * 2048 + k] = v;
}

DINL void ph_combT(int vb, const float* __restrict__ C1P, const float* __restrict__ C2P,
                   float* __restrict__ C1, float* __restrict__ C2, float scale) {
  const int half = vb >> 12;
  const int i = ((vb & 4095) << 8) + threadIdx.x;
  const float* src = half ? C2P : C1P;
  float s = 0.f;
#pragma unroll
  for (int ks = 0; ks < 4; ks++) s += src[ks * 1048576 + i];
  (half ? C2 : C1)[i] = s * scale;
}

DINL void ph_combF(int vb, const float* __restrict__ CfP, float* __restrict__ Cf) {
  const int i2 = vb * 256 + threadIdx.x;
  const int r = i2 >> 11, c = i2 & 2047;
  float s = 0.f;
#pragma unroll
  for (int ks = 0; ks < 4; ks++) s += CfP[ks * 2105344 + r * 2056 + c];
  Cf[r * 2056 + c] = s;
}

DINL void ph_s2b(int vb, const float* __restrict__ s2p, float* __restrict__ state) {
  const int gi = vb * 256 + threadIdx.x;
  const int b = gi >> 10, h = gi & 1023;
  float s = 0.f;
  for (int si = 0; si < 8; si++) s += s2p[((si * 16 + b) << 10) + h];
  state[gi] = tanhf(s);
}

// E (256-thread variant): vb in [0,1024): kc = vb&63 (32 keys), b = vb>>6.
DINL void ph_E(int vb, char* qsm, const float* __restrict__ prompt,
               const float* __restrict__ sqkcP, float* __restrict__ E) {
  const int kc = vb & 63, b = vb >> 6;
  const int t = threadIdx.x;
  for (int idx = t; idx < 9216; idx += 256) {
    const int j = idx >> 10, h = idx & 1023;
    float s = 0.f;
    for (int sp = 0; sp < 4; sp++) s += sqkcP[(sp * 9 + j) * 1025 + h];
    const int x = idx << 2;
    *(float*)(qsm + (x ^ (((x >> 7) & 7) << 4))) = s;
  }
  __syncthreads();
  const int w = t >> 6, l = t & 63;
  const int bxl = 64 * l;
  const int key = ((bxl >> 7) & 7) << 4;
  const int o0 = bxl ^ key, o1 = (bxl + 16) ^ key, o2 = (bxl + 32) ^ key, o3 = (bxl + 48) ^ key;
  const int k0 = kc * 32 + w * 8;
  const float* pbase = prompt + ((b * 2048 + k0) << 10) + 16 * l;
  for (int ki = 0; ki < 8; ki++) {
    const float4* pr = (const float4*)(pbase + (ki << 10));
    const float4 p0 = pr[0], p1 = pr[1], p2 = pr[2], p3 = pr[3];
    float sj[9];
#pragma unroll
    for (int j = 0; j < 9; j++) {
      const char* qp = qsm + (j << 12);
      sj[j] = dot4(*(const float4*)(qp + o0), p0) + dot4(*(const float4*)(qp + o1), p1) +
              dot4(*(const float4*)(qp + o2), p2) + dot4(*(const float4*)(qp + o3), p3);
    }
#pragma unroll
    for (int off = 32; off > 0; off >>= 1) {
#pragma unroll
      for (int j = 0; j < 9; j++) sj[j] += __shfl_xor(sj[j], off);
    }
    float wv = sj[0];
#pragma unroll
    for (int j = 1; j < 9; j++)
      if (l == j) wv = sj[j];
    if (l < 9) E[(b * 2048 + k0 + ki) * 9 + l] = __expf(wv);
  }
}

// ===========================================================================
// merged setup kernels
// ===========================================================================
__global__ __launch_bounds__(256) void k_setup1(const float* prompt, const float* logic,
                                                const float* cbv, const float* Wpv,
                                                const float* Wgate, const float* Wstop,
                                                const float* Wpq, const float* Wsq,
                                                const float* Wpk, float* w) {
  __shared__ __align__(16) float sm[4224];
  const int bx = blockIdx.x;
  if (bx < 512) ph_wgT(bx, sm, Wpq, Wpk, w + F_WQKP, Wsq, w + F_T1P);
  else if (bx < 1536) ph_meanpsum(bx - 512, prompt, w + F_PMP, 2048);
  else if (bx < 1792) ph_meanpsum(bx - 1536, logic, w + F_LMP, 512);
  else if (bx < 3840) ph_cbsq(bx - 1792, cbv, w + F_CBSQ);
  else ph_gs(bx - 3840, Wpv, Wgate, Wstop, w + F_WFUSE);
}

__global__ __launch_bounds__(256) void k_setup2(float* w, float scale) {
  const int bx = blockIdx.x;
  if (bx < 8192) ph_combT(bx, w + F_WQKP, w + F_T1P, w + F_WQK, w + F_T1, scale);
  else ph_meancat(bx - 8192, w + F_PMP, w + F_LMP, w + F_MEAN);
}

__global__ __launch_bounds__(256) void k_setup3(SG pInit, SG pSqkc,
                                                const float* Wpv, const float* Wop,
                                                float* w) {
  __shared__ __align__(16) float As[4352];
  const int bx = blockIdx.x;
  if (bx < 512) ph_wgF(bx, As, Wpv, Wop, w + F_T1, w + F_WFP);
  else if (bx < 640) sgemm_body<4>(pInit, bx - 512, As);
  else sgemm_body<7>(pSqkc, bx - 640, As);
}

__global__ __launch_bounds__(256) void k_setup4(const float* prompt, float* w) {
  __shared__ __align__(16) char qsm[36864];
  const int bx = blockIdx.x;
  if (bx < 1024) ph_E(bx, qsm, prompt, w + F_SQKCP, w + F_E);
  else if (bx < 9216) ph_combF(bx - 1024, w + F_WFP, w + F_WFUSE);
  else ph_s2b(bx - 9216, w + F_S2P, w + F_STATE);
}

// ===========================================================================
// per-iteration phase bodies (R11-verified, flash from R12)
// ===========================================================================

DINL void ph_qs1(int bx, char* smemc, const float* state, const float* Wqk,
                 float* outP) {
  float* As = (float*)smemc;
  const int t = threadIdx.x;
  const int ks = bx >> 4, nb = bx & 15;
  const int kb = ks * 128;
  for (int idx = t; idx < 2048; idx += 256)
    As[idx] = state[((idx >> 7) << 10) + kb + (idx & 127)];
  __syncthreads();
  const int nl = t & 63, mg = t >> 6;
  const int n = nb * 64 + nl;
  const float* Bc = Wqk + n;
  float acc[4] = {0.f, 0.f, 0.f, 0.f};
  for (int k4 = 0; k4 < 128; k4 += 4) {
    float bv[4];
#pragma unroll
    for (int u = 0; u < 4; u++) bv[u] = Bc[(kb + k4 + u) << 10];
#pragma unroll
    for (int i = 0; i < 4; i++) {
      const float4 av = *(const float4*)&As[((mg + 4 * i) << 7) + k4];
      acc[i] = fmaf(av.x, bv[0], acc[i]);
      acc[i] = fmaf(av.y, bv[1], acc[i]);
      acc[i] = fmaf(av.z, bv[2], acc[i]);
      acc[i] = fmaf(av.w, bv[3], acc[i]);
    }
  }
#pragma unroll
  for (int i = 0; i < 4; i++)
    outP[((ks * 16 + mg + 4 * i) << 10) + n] = acc[i];
}

// flash with block-level reduce (R12-verified): grid (64,16).
DINL void ph_flash(int g, int b, char* smemc, const float* prompt,
                   const float* qs1P, float* accsm, float* lsm) {
  float* red = (float*)smemc;            // 4*1024 floats
  float* lred = (float*)(smemc + 16384); // 4 floats
  const int t = threadIdx.x;
  const int w = t >> 6, l = t & 63;
  float4 q0 = make_float4(0.f, 0.f, 0.f, 0.f), q1 = q0, q2 = q0, q3 = q0;
#pragma unroll
  for (int s = 0; s < 8; s++) {
    const float4* qp = (const float4*)(qs1P + ((s * 16 + b) << 10) + 16 * l);
    ADD4(q0, qp[0]); ADD4(q1, qp[1]); ADD4(q2, qp[2]); ADD4(q3, qp[3]);
  }
  float4 acc[4];
#pragma unroll
  for (int r = 0; r < 4; r++) acc[r] = make_float4(0.f, 0.f, 0.f, 0.f);
  float lsum = 0.f;
  const int k0 = g * 32 + w * 8;
  const float* pbase = prompt + ((b * 2048 + k0) << 10) + 16 * l;
#pragma unroll 2
  for (int k = 0; k < 8; k++) {
    const float4* pr = (const float4*)(pbase + (k << 10));
    const float4 p0 = pr[0], p1 = pr[1], p2 = pr[2], p3 = pr[3];
    float s = dot4(q0, p0) + dot4(q1, p1) + dot4(q2, p2) + dot4(q3, p3);
#pragma unroll
    for (int off = 32; off > 0; off >>= 1) s += __shfl_xor(s, off);
    const float wgt = __expf(s);
    lsum += wgt;
    AXPY4(acc[0], wgt, p0); AXPY4(acc[1], wgt, p1);
    AXPY4(acc[2], wgt, p2); AXPY4(acc[3], wgt, p3);
  }
  float4* myr = (float4*)(red + w * 1024 + 16 * l);
  myr[0] = acc[0]; myr[1] = acc[1]; myr[2] = acc[2]; myr[3] = acc[3];
  if (l == 0) lred[w] = lsum;
  __syncthreads();
  float4 s0 = *(float4*)(red + t * 4);
  const float4 s1 = *(float4*)(red + 1024 + t * 4);
  const float4 s2 = *(float4*)(red + 2048 + t * 4);
  const float4 s3 = *(float4*)(red + 3072 + t * 4);
  ADD4(s0, s1); ADD4(s0, s2); ADD4(s0, s3);
  *(float4*)&accsm[((b * 64 + g) << 10) + t * 4] = s0;
  if (t == 0) lsm[b * 64 + g] = lred[0] + lred[1] + lred[2] + lred[3];
}

// cst over 64 block-psums: ctx[b][h] = sum_g accsm / sum_g lsm. grid 256.
DINL void ph_cst(int bx, char* smemc, const float* accsm, const float* lsm,
                 float* ctx) {
  float4* sred = (float4*)smemc;
  float* rinvp = (float*)(smemc + 4096);
  const int b = bx >> 4, hq = bx & 15;
  const int t = threadIdx.x;
  if (t < 64) {
    float s = lsm[b * 64 + t];
#pragma unroll
    for (int off = 32; off > 0; off >>= 1) s += __shfl_xor(s, off);
    if (t == 0) rinvp[0] = 1.f / s;
  }
  const int h4 = hq * 16 + (t & 15);
  const int gp = t >> 4;
  float4 a = make_float4(0.f, 0.f, 0.f, 0.f);
#pragma unroll
  for (int gi = 0; gi < 4; gi++) {
    const int g = gp * 4 + gi;
    const float4 v = ((const float4*)accsm)[((b * 64 + g) << 8) + h4];
    ADD4(a, v);
  }
  sred[t] = a;
  __syncthreads();
  if (t < 16) {
    float4 s = sred[t];
    for (int p2 = 1; p2 < 16; p2++) {
      const float4 v = sred[p2 * 16 + t];
      ADD4(s, v);
    }
    const float rinv = rinvp[0];
    s.x *= rinv; s.y *= rinv; s.z *= rinv; s.w *= rinv;
    ((float4*)ctx)[(b << 8) + hq * 16 + t] = s;
  }
}

DINL void ph_fw(int bx, char* smemc, const float* ctx, const float* wfuse,
                float* outp) {
  float* As = (float*)smemc;
  const int t = threadIdx.x;
  const int ks = bx / 33, nb = bx % 33;
  const int kb = ks * 64;
  for (int idx = t; idx < 1024; idx += 256)
    As[idx] = ctx[((idx >> 6) << 10) + kb + (idx & 63)];
  __syncthreads();
  const int nl = t & 63, mg = t >> 6;
  const int n = nb * 64 + nl;
  const bool nok = (n < 2050);
  const float* Bc = wfuse + n;
  float acc[4] = {0.f, 0.f, 0.f, 0.f};
  for (int k4 = 0; k4 < 64; k4 += 4) {
    float bv[4];
#pragma unroll
    for (int u = 0; u < 4; u++) bv[u] = nok ? Bc[(kb + k4 + u) * 2056] : 0.f;
#pragma unroll
    for (int i = 0; i < 4; i++) {
      const float4 av = *(const float4*)&As[((mg + 4 * i) << 6) + k4];
      acc[i] = fmaf(av.x, bv[0], acc[i]);
      acc[i] = fmaf(av.y, bv[1], acc[i]);
      acc[i] = fmaf(av.z, bv[2], acc[i]);
      acc[i] = fmaf(av.w, bv[3], acc[i]);
    }
  }
  if (nok) {
#pragma unroll
    for (int i = 0; i < 4; i++) outp[(ks * 16 + mg + 4 * i) * 2056 + n] = acc[i];
  }
}

DINL void ph_combw(int bx, const float* fwP, const float* sqkcP, float* opv,
                   float* qslb, float* gpre, float* gc, float* stopA) {
  const int t = threadIdx.x;
  if (bx < 64) {
    const int i = bx * 256 + t;
    const int b = i >> 10, h = i & 1023;
    float s = 0.f;
    for (int p = 0; p < 16; p++) s += fwP[(p * 16 + b) * 2056 + h];
    opv[i] = s;
  } else if (bx < 128) {
    const int i = (bx - 64) * 256 + t;
    const int b = i >> 10, h = i & 1023;
    float s = 0.f;
    for (int p = 0; p < 16; p++) s += fwP[(p * 16 + b) * 2056 + 1024 + h];
    qslb[i] = s;
  } else {
    if (t < 16) {
      float g = 0.f, sa = 0.f;
      for (int p = 0; p < 16; p++) {
        g += fwP[(p * 16 + t) * 2056 + 2048];
        sa += fwP[(p * 16 + t) * 2056 + 2049];
      }
      gpre[t] = g;
      stopA[t] = sa;
    } else if (t < 25) {
      const int j = t - 16;
      float g = 0.f;
      for (int sp = 0; sp < 4; sp++) g += sqkcP[(sp * 9 + j) * 1025 + 1024];
      gc[j] = g;
    }
  }
}

DINL void ph_slot(int vb, char* smemc, const float* prompt, const float* qslb,
                  const float* E, float* accp, float* lpsum) {
  float* wl = (float*)smemc;
  float* lred = (float*)(smemc + 2560);
  const int kc = vb & 31, b = vb >> 5;
  const int t = threadIdx.x;
  const int w = t >> 6, l = t & 63;
  const float4* qp = (const float4*)(qslb + (b << 10) + 16 * l);
  const float4 q0 = qp[0], q1 = qp[1], q2 = qp[2], q3 = qp[3];
  const int kbase = kc * 64 + w * 16;
  float lacc = 0.f;
  const float* pbase = prompt + ((b * 2048 + kbase) << 10) + 16 * l;
  for (int ki = 0; ki < 16; ki++) {
    const float4* pr = (const float4*)(pbase + (ki << 10));
    const float4 p0 = pr[0], p1 = pr[1], p2 = pr[2], p3 = pr[3];
    float s = dot4(q0, p0) + dot4(q1, p1) + dot4(q2, p2) + dot4(q3, p3);
#pragma unroll
    for (int off = 32; off > 0; off >>= 1) s += __shfl_xor(s, off);
    const float we = __expf(s);
    if (l < 9) {
      const float wv = we * E[(b * 2048 + kbase + ki) * 9 + l];
      wl[(w * 16 + ki) * 10 + l] = wv;
      lacc += wv;
    }
  }
  if (l < 9) lred[w * 9 + l] = lacc;
  __syncthreads();
  if (t < 9)
    lpsum[(b * 32 + kc) * 9 + t] = lred[t] + lred[9 + t] + lred[18 + t] + lred[27 + t];
  const int h4 = (w << 8) + (l << 2);
  float4 acc[9];
#pragma unroll
  for (int j = 0; j < 9; j++) acc[j] = make_float4(0.f, 0.f, 0.f, 0.f);
  const float* pb2 = prompt + ((b * 2048 + kc * 64) << 10) + h4;
#pragma unroll 2
  for (int k = 0; k < 64; k++) {
    const float4 pv = *(const float4*)(pb2 + (k << 10));
    const float* wr = &wl[k * 10];
#pragma unroll
    for (int j = 0; j < 9; j++) AXPY4(acc[j], wr[j], pv);
  }
  float* ob = accp + (((kc * 16 + b) * 9) << 10) + h4;
#pragma unroll
  for (int j = 0; j < 9; j++) *(float4*)(ob + (j << 10)) = acc[j];
}

DINL void ph_cb(int vb, char* smemc, const float* opv, const float* cbv,
                const float* cbsqv, unsigned long long* opmaxp) {
  const int t = threadIdx.x;
  const int w = t >> 6, l = t & 63;
  const int bxl = 64 * l;
  const int key = ((bxl >> 7) & 7) << 4;
  const int o0 = bxl ^ key, o1 = (bxl + 16) ^ key, o2 = (bxl + 32) ^ key, o3 = (bxl + 48) ^ key;
  for (int half = 0; half < 2; half++) {
    __syncthreads();
    for (int idx = t; idx < 8192; idx += 256) {
      const int x = idx << 2;
      *(float*)(smemc + (x ^ (((x >> 7) & 7) << 4))) = opv[half * 8192 + idx];
    }
    __syncthreads();
    unsigned long long bk[8];
#pragma unroll
    for (int m = 0; m < 8; m++) bk[m] = 0ull;
    const int cbase = (vb << 4) + (w << 2);
    for (int ci = 0; ci < 4; ci++) {
      const int c = cbase + ci;
      const float4* cr = (const float4*)(cbv + (c << 10));
      const float4 c0 = cr[4 * l], c1 = cr[4 * l + 1], c2 = cr[4 * l + 2], c3 = cr[4 * l + 3];
      float sm[8];
#pragma unroll
      for (int m = 0; m < 8; m++) {
        const char* qp = smemc + (m << 12);
        const float4 a0 = *(const float4*)(qp + o0);
        const float4 a1 = *(const float4*)(qp + o1);
        const float4 a2 = *(const float4*)(qp + o2);
        const float4 a3 = *(const float4*)(qp + o3);
        sm[m] = dot4(a0, c0) + dot4(a1, c1) + dot4(a2, c2) + dot4(a3, c3);
      }
#pragma unroll
      for (int off = 32; off > 0; off >>= 1) {
#pragma unroll
        for (int m = 0; m < 8; m++) sm[m] += __shfl_xor(sm[m], off);
      }
      const float cq = cbsqv[c];
#pragma unroll
      for (int m = 0; m < 8; m++) {
        const float sc = fmaf(2.f, sm[m], -cq);
        const unsigned long long k2 =
            ((unsigned long long)sortable(sc) << 32) | (unsigned)(8192 - c);
        bk[m] = k2 > bk[m] ? k2 : bk[m];
      }
    }
    unsigned long long* red = (unsigned long long*)(smemc + 32768);
    __syncthreads();
    if (l == 0) {
#pragma unroll
      for (int m = 0; m < 8; m++) red[w * 8 + m] = bk[m];
    }
    __syncthreads();
    if (t < 8) {
      unsigned long long b2 = red[t];
      for (int ww = 1; ww < 4; ww++) {
        const unsigned long long v = red[ww * 8 + t];
        b2 = v > b2 ? v : b2;
      }
      opmaxp[vb * 16 + half * 8 + t] = b2;
    }
  }
}

DINL void ph_k7(int bx, char* smemc, const float* accp, const float* lpsum,
                const float* gpre_g, const float* gc_g, const float* bgate,
                const unsigned long long* opmax, int* opidx, float* ssum) {
  unsigned long long* red = (unsigned long long*)smemc;
  float* rl = (float*)(smemc + 2048);
  float* gpre = (float*)(smemc + 2112);
  float* gcs = (float*)(smemc + 2192);
  int* mask_s = (int*)(smemc + 2240);
  float* cntInvp = (float*)(smemc + 2288);
  const int t = threadIdx.x;
  if (bx == 64) {
    const int b = t & 15, part = t >> 4;
    unsigned long long best = 0ull;
    for (int c = part * 32; c < part * 32 + 32; c++) {
      const unsigned long long v = opmax[c * 16 + b];
      best = v > best ? v : best;
    }
    red[t] = best;
    __syncthreads();
    if (t < 16) {
      unsigned long long m = red[t];
      for (int p2 = 1; p2 < 16; p2++) {
        const unsigned long long v = red[p2 * 16 + t];
        m = v > m ? v : m;
      }
      opidx[t] = 8192 - (int)(unsigned)(m & 0xFFFFFFFFull);
    }
    return;
  }
  const int b = bx >> 2;
  if (t < 9) {
    float s = 0.f;
    for (int c = 0; c < 32; c++) s += lpsum[(b * 32 + c) * 9 + t];
    rl[t] = 1.f / s;
  }
  if (t >= 32 && t < 48) gpre[t - 32] = gpre_g[t - 32];
  if (t >= 48 && t < 57) gcs[t - 48] = gc_g[t - 48];
  __syncthreads();
  if (t == 0) {
    const float bg = bgate[0];
    bool any = false;
    for (int bb = 0; bb < 16; bb++)
      for (int j = 0; j < 9; j++)
        if (gpre[bb] + gcs[j] + bg >= 0.f) any = true;
    int cnt = 0;
    if (any) {
      for (int j = 0; j < 9; j++) {
        const int s = (gpre[b] + gcs[j] + bg >= 0.f) ? 1 : 0;
        mask_s[j] = s;
        cnt += s;
      }
    } else {
      float bv = -3.4e38f;
      int bj = 0;
      for (int j = 0; j < 9; j++) {
        const float v = gpre[b] + gcs[j] + bg;
        if (v > bv) { bv = v; bj = j; }
      }
      for (int j = 0; j < 9; j++) mask_s[j] = (j == bj) ? 1 : 0;
      cnt = 1;
    }
    cntInvp[0] = 1.f / (float)(cnt > 0 ? cnt : 1);
  }
  __syncthreads();
  const int h = ((bx & 3) << 8) + t;
  float v = 0.f;
  for (int j = 0; j < 9; j++) {
    if (mask_s[j]) {
      float s = 0.f;
      for (int c = 0; c < 32; c++) s += accp[(((c * 16 + b) * 9 + j) << 10) + h];
      v = fmaf(s, rl[j], v);
    }
  }
  ssum[(b << 10) + h] = v * cntInvp[0];
}

DINL void ph_k8p(int bx, char* smemc, const float* ssum, const float* Wpv,
                 float* outP) {
  float* As = (float*)smemc;
  const int t = threadIdx.x;
  const int ks = bx >> 4, nb = bx & 15;
  const int kb = ks * 64;
  for (int idx = t; idx < 1024; idx += 256)
    As[idx] = ssum[((idx >> 6) << 10) + kb + (idx & 63)];
  __syncthreads();
  const int nl = t & 63, mg = t >> 6;
  const int n = nb * 64 + nl;
  const float* Bc = Wpv + n;
  float acc[4] = {0.f, 0.f, 0.f, 0.f};
  for (int k4 = 0; k4 < 64; k4 += 4) {
    float bv[4];
#pragma unroll
    for (int u = 0; u < 4; u++) bv[u] = Bc[(kb + k4 + u) << 10];
#pragma unroll
    for (int i = 0; i < 4; i++) {
      const float4 av = *(const float4*)&As[((mg + 4 * i) << 6) + k4];
      acc[i] = fmaf(av.x, bv[0], acc[i]);
      acc[i] = fmaf(av.y, bv[1], acc[i]);
      acc[i] = fmaf(av.z, bv[2], acc[i]);
      acc[i] = fmaf(av.w, bv[3], acc[i]);
    }
  }
#pragma unroll
  for (int i = 0; i < 4; i++)
    outP[((ks * 16 + mg + 4 * i) << 10) + n] = acc[i];
}

DINL void ph_gru(int bx, char* smemc, const float* k8p, const int* opidx,
                 const float* cbv, const float* state, const float* Wih,
                 const float* Whh, float* gpP, float* ms, float* dout, int it) {
  float* As = (float*)smemc;
  const int t = threadIdx.x;
  const int half = (bx >= 384) ? 1 : 0;
  const int b2 = half ? bx - 384 : bx;
  const int ks = b2 / 48, nb = b2 % 48;
  const int kb = ks * 128;
  for (int idx = t; idx < 2048; idx += 256) {
    const int m = idx >> 7, kl = idx & 127;
    float v;
    if (!half) {
      float s = 0.f;
      for (int p = 0; p < 16; p++) s += k8p[((p * 16 + m) << 10) + kb + kl];
      v = tanhf(s + cbv[(opidx[m] << 10) + kb + kl]);
      if (nb == 0) {
        ms[(m << 10) + kb + kl] = v;
        dout[(m << 12) + (it << 10) + kb + kl] = v;
      }
    } else {
      v = state[(m << 10) + kb + kl];
    }
    As[idx] = v;
  }
  __syncthreads();
  const int nl = t & 63, mg = t >> 6;
  const int n = nb * 64 + nl;
  const float* Bc = (half ? Whh : Wih) + n;
  float acc[4] = {0.f, 0.f, 0.f, 0.f};
  for (int k4 = 0; k4 < 128; k4 += 4) {
    float bv[4];
#pragma unroll
    for (int u = 0; u < 4; u++) bv[u] = Bc[(kb + k4 + u) * 3072];
#pragma unroll
    for (int i = 0; i < 4; i++) {
      const float4 av = *(const float4*)&As[((mg + 4 * i) << 7) + k4];
      acc[i] = fmaf(av.x, bv[0], acc[i]);
      acc[i] = fmaf(av.y, bv[1], acc[i]);
      acc[i] = fmaf(av.z, bv[2], acc[i]);
      acc[i] = fmaf(av.w, bv[3], acc[i]);
    }
  }
  float* outp = gpP + half * 3072;
#pragma unroll
  for (int i = 0; i < 4; i++) outp[(ks * 16 + mg + 4 * i) * 6144 + n] = acc[i];
}

DINL void ph_k9b(int bx, const float* gp, const float* bih, const float* bhh,
                 float* state, const float* stopA, const float* ms,
                 const float* Wstop, const float* bstop, float* dout, int it) {
  const int t = threadIdx.x;
  if (bx < 64) {
    const int gi = bx * 256 + t;
    const int b = gi >> 10, h = gi & 1023;
    float ir = 0.f, iz = 0.f, inn = 0.f, hr = 0.f, hz = 0.f, hn = 0.f;
    for (int s = 0; s < 8; s++) {
      const float* g = gp + (s * 16 + b) * 6144;
      ir += g[h]; iz += g[1024 + h]; inn += g[2048 + h];
      hr += g[3072 + h]; hz += g[4096 + h]; hn += g[5120 + h];
    }
    ir += bih[h]; iz += bih[1024 + h]; inn += bih[2048 + h];
    hr += bhh[h]; hz += bhh[1024 + h]; hn += bhh[2048 + h];
    const float r = 1.f / (1.f + __expf(-(ir + hr)));
    const float z = 1.f / (1.f + __expf(-(iz + hz)));
    const float n = tanhf(fmaf(r, hn, inn));
    const float hold = state[gi];
    state[gi] = (1.f - z) * n + z * hold;
  } else {
    const int wid = (bx - 64) * 4 + (t >> 6);
    const int l = t & 63;
    float p = 0.f;
    for (int i = 0; i < 16; i++) {
      const int h = l + (i << 6);
      p = fmaf(ms[(wid << 10) + h], Wstop[1024 + h], p);
    }
#pragma unroll
    for (int off = 32; off > 0; off >>= 1) p += __shfl_xor(p, off);
    if (l == 0) {
      const float lg = p + stopA[wid] + bstop[0];
      dout[65536 + wid * 4 + it] = lg;
      dout[65600 + wid * 4 + it] = 1.f / (1.f + __expf(-lg));
    }
  }
}

// ===========================================================================
// per-iteration kernels
// ===========================================================================
__global__ __launch_bounds__(256) void kf_qs1(const float* state, const float* Wqk, float* outP) {
  __shared__ __align__(16) char smem[8192];
  ph_qs1(blockIdx.x, smem, state, Wqk, outP);
}
__global__ __launch_bounds__(256) void kf_flash(const float* prompt, const float* qs1P,
                                                float* accsm, float* lsm) {
  __shared__ __align__(16) char smem[16416];
  ph_flash(blockIdx.x, blockIdx.y, smem, prompt, qs1P, accsm, lsm);
}
__global__ __launch_bounds__(256) void kf_cst(const float* accsm, const float* lsm, float* ctx) {
  __shared__ __align__(16) char smem[4112];
  ph_cst(blockIdx.x, smem, accsm, lsm, ctx);
}
__global__ __launch_bounds__(256) void kf_fw(const float* ctx, const float* wfuse, float* outp) {
  __shared__ __align__(16) char smem[4096];
  ph_fw(blockIdx.x, smem, ctx, wfuse, outp);
}
__global__ __launch_bounds__(256) void kf_combw(const float* fwP, const float* sqkcP,
                                                float* opv, float* qslb, float* gpre,
                                                float* gc, float* stopA) {
  ph_combw(blockIdx.x, fwP, sqkcP, opv, qslb, gpre, gc, stopA);
}
__global__ __launch_bounds__(256) void k_slotcb(const float* prompt, const float* qslb,
                                                const float* E, float* accp, float* lpsum,
                                                const float* opv, const float* cbv,
                                                const float* cbsqv,
                                                unsigned long long* opmaxp) {
  __shared__ __align__(16) char smem[33024];
  const int bx = blockIdx.x;
  if (bx < 512) ph_slot(bx, smem, prompt, qslb, E, accp, lpsum);
  else ph_cb(bx - 512, smem, opv, cbv, cbsqv, opmaxp);
}
__global__ __launch_bounds__(256) void kf_k7(const float* accp, const float* lpsum,
                                             const float* gpre_g, const float* gc_g,
                                             const float* bgate,
                                             const unsigned long long* opmax,
                                             int* opidx, float* ssum) {
  __shared__ __align__(16) char smem[2304];
  ph_k7(blockIdx.x, smem, accp, lpsum, gpre_g, gc_g, bgate, opmax, opidx, ssum);
}
__global__ __launch_bounds__(256) void kf_k8p(const float* ssum, const float* Wpv, float* outP) {
  __shared__ __align__(16) char smem[4096];
  ph_k8p(blockIdx.x, smem, ssum, Wpv, outP);
}
__global__ __launch_bounds__(256) void kf_gru(const float* k8p, const int* opidx,
                                              const float* cbv, const float* state,
                                              const float* Wih, const float* Whh,
                                              float* gpP, float* ms, float* dout, int it) {
  __shared__ __align__(16) char smem[8192];
  ph_gru(blockIdx.x, smem, k8p, opidx, cbv, state, Wih, Whh, gpP, ms, dout, it);
}
__global__ __launch_bounds__(256) void kf_k9b(const float* gp, const float* bih,
                                              const float* bhh, float* state,
                                              const float* stopA, const float* ms,
                                              const float* Wstop, const float* bstop,
                                              float* dout, int it) {
  ph_k9b(blockIdx.x, gp, bih, bhh, state, stopA, ms, Wstop, bstop, dout, it);
}
__global__ void kf_k10(float* __restrict__ dout) {
  const int t = threadIdx.x;
  if (t < 16) {
    int cl = 4;
    for (int it = 0; it < 4; it++) {
      if (dout[65536 + t * 4 + it] >= 0.f) { cl = it + 1; break; }
    }
    dout[65664 + t] = (float)cl;
  }
}

// ===========================================================================
// host
// ===========================================================================
extern "C" void kernel_launch(void* const* d_in, const int* in_sizes, int n_in,
                              void* d_out, int out_size, void* d_ws, size_t ws_size,
                              hipStream_t stream) {
  (void)in_sizes; (void)n_in; (void)out_size; (void)ws_size;
  const float* logic  = (const float*)d_in[0];
  const float* prompt = (const float*)d_in[1];
  const float* cbv    = (const float*)d_in[2];
  const float* W_init = (const float*)d_in[3];
  const float* W_pq   = (const float*)d_in[4];
  const float* W_pk   = (const float*)d_in[5];
  const float* W_pv   = (const float*)d_in[6];
  const float* slotq  = (const float*)d_in[7];
  const float* W_sq   = (const float*)d_in[8];
  const float* W_op   = (const float*)d_in[9];
  const float* W_gate = (const float*)d_in[10];
  const float* b_gate = (const float*)d_in[11];
  const float* W_stop = (const float*)d_in[12];
  const float* b_stop = (const float*)d_in[13];
  const float* Wih    = (const float*)d_in[14];
  const float* Whh    = (const float*)d_in[15];
  const float* bih    = (const float*)d_in[16];
  const float* bhh    = (const float*)d_in[17];
  float* out = (float*)d_out;
  float* w = (float*)d_ws;

  const float inv32 = 1.0f / 32.0f;

  // D1: wgT | meanpsum(prompt) | meanpsum(logic) | cbsq | gs
  k_setup1<<<3904, 256, 0, stream>>>(prompt, logic, cbv, W_pv, W_gate, W_stop,
                                     W_pq, W_sq, W_pk, w);
  // D2: combT | meancat
  k_setup2<<<8320, 256, 0, stream>>>(w, inv32);
  // D3: wgF | init-GEMM | sqkc-GEMM
  {
    SG pInit;
    pInit.Bm = W_init; pInit.Bg = nullptr; pInit.a0 = w + F_MEAN;
    pInit.out = w + F_S2P;
    pInit.M = 16; pInit.N = 1024; pInit.Ncore = 1024; pInit.NB = 16;
    pInit.kslice = 256; pInit.ksh = 8; pInit.lda = 2048; pInit.ldb = 1024;
    pInit.ldo = 1024; pInit.mr = 4; pInit.scale = 1.f;
    SG pSqkc;
    pSqkc.Bm = w + F_T1; pSqkc.Bg = W_gate; pSqkc.a0 = slotq;
    pSqkc.out = w + F_SQKCP;
    pSqkc.M = 9; pSqkc.N = 1025; pSqkc.Ncore = 1024; pSqkc.NB = 17;
    pSqkc.kslice = 256; pSqkc.ksh = 8; pSqkc.lda = 1024; pSqkc.ldb = 1024;
    pSqkc.ldo = 1025; pSqkc.mr = 7; pSqkc.scale = 1.f;
    k_setup3<<<708, 256, 0, stream>>>(pInit, pSqkc, W_pv, W_op, w);
  }
  // D4: E | combF | s2b
  k_setup4<<<9280, 256, 0, stream>>>(prompt, w);

  // ---- iteration loop (10 dispatches/iter) ----
  for (int it = 0; it < 4; ++it) {
    kf_qs1<<<128, 256, 0, stream>>>(w + F_STATE, w + F_WQK, w + F_QS1);
    kf_flash<<<dim3(64, 16), 256, 0, stream>>>(prompt, w + F_QS1,
                                               w + F_ACCSM, w + F_LSM);
    kf_cst<<<256, 256, 0, stream>>>(w + F_ACCSM, w + F_LSM, w + F_CTX);
    kf_fw<<<528, 256, 0, stream>>>(w + F_CTX, w + F_WFUSE, w + F_FWP);
    kf_combw<<<129, 256, 0, stream>>>(w + F_FWP, w + F_SQKCP, w + F_OPV,
                                      w + F_QSLB, w + F_GPRE, w + F_GC, w + F_STOPA);
    k_slotcb<<<1024, 256, 0, stream>>>(prompt, w + F_QSLB, w + F_E,
                                       w + F_ACCP, w + F_LPS, w + F_OPV, cbv,
                                       w + F_CBSQ,
                                       (unsigned long long*)(w + F_OPMAX));
    kf_k7<<<65, 256, 0, stream>>>(w + F_ACCP, w + F_LPS, w + F_GPRE, w + F_GC,
                                  b_gate, (const unsigned long long*)(w + F_OPMAX),
                                  (int*)(w + F_OPIDX), w + F_SSUM);
    kf_k8p<<<256, 256, 0, stream>>>(w + F_SSUM, W_pv, w + F_K8P);
    kf_gru<<<768, 256, 0, stream>>>(w + F_K8P, (const int*)(w + F_OPIDX), cbv,
                                    w + F_STATE, Wih, Whh, w + F_GP, w + F_MS,
                                    out, it);
    kf_k9b<<<68, 256, 0, stream>>>(w + F_GP, bih, bhh, w + F_STATE, w + F_STOPA,
                                   w + F_MS, W_stop, b_stop, out, it);
  }
  kf_k10<<<1, 64, 0, stream>>>(out);
}